// Round 6
// baseline (954.903 us; speedup 1.0000x reference)
//
#include <hip/hip_runtime.h>
#include <math.h>

#define NN 50000
#define EE 500000
#define DIN 128
#define HH 256
#define PP 100000

typedef unsigned short ushortT;
typedef short bf16x8 __attribute__((ext_vector_type(8)));   // 8 bf16 in 4 VGPRs
typedef float f32x4 __attribute__((ext_vector_type(4)));

// ---- bf16 helpers (RNE) ----
__device__ __forceinline__ ushortT f2bf(float f) {
  unsigned u = __float_as_uint(f);
  unsigned r = u + 0x7FFFu + ((u >> 16) & 1u);
  return (ushortT)(r >> 16);
}
__device__ __forceinline__ float bf2f(ushortT h) {
  return __uint_as_float(((unsigned)h) << 16);
}

// async global->LDS, 16B per lane. LDS dest must be wave-uniform base (+lane*16 implicit).
__device__ __forceinline__ void gld16(const void* g, void* l) {
  __builtin_amdgcn_global_load_lds((const __attribute__((address_space(1))) void*)g,
                                   (__attribute__((address_space(3))) void*)l, 16, 0, 0);
}

// ---------------- CSR build ----------------

__global__ __launch_bounds__(256) void count_deg(const int* __restrict__ dst,
                                                 int* __restrict__ cnt, int n) {
  int i = blockIdx.x * 256 + threadIdx.x;
  if (i < n) atomicAdd(&cnt[dst[i]], 1);
}

__global__ __launch_bounds__(256) void compute_dinv(const int* __restrict__ cnt,
                                                    float* __restrict__ dinv, int n) {
  int i = blockIdx.x * 256 + threadIdx.x;
  if (i < n) dinv[i] = rsqrtf((float)(cnt[i] + 1));  // +1 self-loop
}

__global__ __launch_bounds__(256) void scan_block(const int* __restrict__ cnt,
                                                  int* __restrict__ outp,
                                                  int* __restrict__ bsum, int n) {
  __shared__ int s[256];
  int i = blockIdx.x * 256 + threadIdx.x;
  int v = (i < n) ? cnt[i] : 0;
  s[threadIdx.x] = v;
  __syncthreads();
  for (int off = 1; off < 256; off <<= 1) {
    int t = (threadIdx.x >= off) ? s[threadIdx.x - off] : 0;
    __syncthreads();
    s[threadIdx.x] += t;
    __syncthreads();
  }
  if (i < n) outp[i] = s[threadIdx.x] - v;
  if (threadIdx.x == 255) bsum[blockIdx.x] = s[255];
}

// parallel exclusive scan over <=256 block sums (was a serial 1-thread loop)
__global__ __launch_bounds__(256) void scan_totals(int* __restrict__ bsum, int nb) {
  __shared__ int s[256];
  int t = threadIdx.x;
  int v = (t < nb) ? bsum[t] : 0;
  s[t] = v;
  __syncthreads();
  for (int off = 1; off < 256; off <<= 1) {
    int u = (t >= off) ? s[t - off] : 0;
    __syncthreads();
    s[t] += u;
    __syncthreads();
  }
  if (t < nb) bsum[t] = s[t] - v;  // exclusive
}

__global__ __launch_bounds__(256) void scan_add(int* __restrict__ indptr,
                                                const int* __restrict__ bsum,
                                                const int* __restrict__ cnt, int n) {
  int i = blockIdx.x * 256 + threadIdx.x;
  if (i < n) {
    int v = indptr[i] + bsum[blockIdx.x];
    indptr[i] = v;
    if (i == n - 1) indptr[n] = v + cnt[i];
  }
}

// fill CSR and precompute edge weight wn = dinv[src]*dinv[dst]
__global__ __launch_bounds__(256) void fill_csr(const int* __restrict__ src,
                                                const int* __restrict__ dst,
                                                const int* __restrict__ indptr,
                                                const float* __restrict__ dinv,
                                                int* __restrict__ fill,
                                                int* __restrict__ col,
                                                float* __restrict__ wn, int n) {
  int i = blockIdx.x * 256 + threadIdx.x;
  if (i < n) {
    int d = dst[i];
    int s = src[i];
    int p = atomicAdd(&fill[d], 1);
    int idx = indptr[d] + p;
    col[idx] = s;
    wn[idx] = dinv[s] * dinv[d];
  }
}

// ---------------- precision-split kernels ----------------

__global__ __launch_bounds__(256) void split_x(const float* __restrict__ x,
                                               ushortT* __restrict__ hi,
                                               ushortT* __restrict__ lo, int n4) {
  int i = blockIdx.x * 256 + threadIdx.x;
  if (i >= n4) return;
  float4 v = ((const float4*)x)[i];
  ushort4 h, l;
  h.x = f2bf(v.x); l.x = f2bf(v.x - bf2f(h.x));
  h.y = f2bf(v.y); l.y = f2bf(v.y - bf2f(h.y));
  h.z = f2bf(v.z); l.z = f2bf(v.z - bf2f(h.z));
  h.w = f2bf(v.w); l.w = f2bf(v.w - bf2f(h.w));
  ((ushort4*)hi)[i] = h;
  ((ushort4*)lo)[i] = l;
}

// W [K][256] fp32 -> Wt hi/lo [256][K] bf16 (transpose + split), tiny
__global__ __launch_bounds__(256) void split_w_t(const float* __restrict__ W,
                                                 ushortT* __restrict__ Whi,
                                                 ushortT* __restrict__ Wlo, int K) {
  int idx = blockIdx.x * 256 + threadIdx.x;
  if (idx >= K * 256) return;
  int k = idx >> 8, n = idx & 255;
  float v = W[idx];
  ushortT h = f2bf(v);
  Whi[(size_t)n * K + k] = h;
  Wlo[(size_t)n * K + k] = f2bf(v - bf2f(h));
}

// ---------------- MFMA GEMM (double-buffered): C[M][256] = A[M][K] @ Wt^T ----------------
// 256 threads = 4 waves; tile 64 rows x 256 cols; bf16x3: Ah*Bh + Al*Bh + Ah*Bl.
// Per-buffer layout (40KB): Ahi[0,4K) Alo[4K,8K) Bhi[8K,24K) Blo[24K,40K). 2 buffers = 80KB.

__device__ __forceinline__ void stage_gemm(const ushortT* __restrict__ Ahi,
                                           const ushortT* __restrict__ Alo,
                                           const ushortT* __restrict__ Bhi,
                                           const ushortT* __restrict__ Blo,
                                           unsigned char* buf, size_t abase, int k0,
                                           int K, int w, int l) {
  gld16(Ahi + abase + k0, buf + w * 1024);
  gld16(Alo + abase + k0, buf + 4096 + w * 1024);
  size_t bkoff = (size_t)(l >> 4) * 8;
#pragma unroll
  for (int r = 0; r < 4; ++r) {
    int col = (r * 4 + w) * 16 + (l & 15);
    size_t boff = (size_t)col * K + k0 + bkoff;
    gld16(Bhi + boff, buf + 8192 + r * 4096 + w * 1024);
    gld16(Blo + boff, buf + 24576 + r * 4096 + w * 1024);
  }
}

__global__ __launch_bounds__(256) void gemm_mfma(const ushortT* __restrict__ Ahi,
                                                 const ushortT* __restrict__ Alo,
                                                 const ushortT* __restrict__ Bhi,
                                                 const ushortT* __restrict__ Blo,
                                                 float* __restrict__ C, int M, int K) {
  __shared__ __align__(16) unsigned char smem[81920];
  int tid = threadIdx.x;
  int w = tid >> 6, l = tid & 63;
  int row0 = blockIdx.x * 64;

  f32x4 acc[16];
#pragma unroll
  for (int c = 0; c < 16; ++c) acc[c] = (f32x4)(0.f);

  int arow = w * 16 + (l & 15);
  int grow = row0 + arow;
  if (grow >= M) grow = M - 1;
  const size_t abase = (size_t)grow * K + (size_t)(l >> 4) * 8;

  stage_gemm(Ahi, Alo, Bhi, Blo, smem, abase, 0, K, w, l);
  __syncthreads();  // drains vmcnt(0): tile 0 ready

  for (int k0 = 0; k0 < K; k0 += 32) {
    unsigned char* cur = smem + ((k0 >> 5) & 1) * 40960;
    unsigned char* nxt = smem + (((k0 >> 5) & 1) ^ 1) * 40960;
    if (k0 + 32 < K)  // issue next-tile loads; they fly under the MFMA phase
      stage_gemm(Ahi, Alo, Bhi, Blo, nxt, abase, k0 + 32, K, w, l);
    bf16x8 ah = *(const bf16x8*)(cur + tid * 16);
    bf16x8 al = *(const bf16x8*)(cur + 4096 + tid * 16);
#pragma unroll
    for (int c = 0; c < 16; ++c) {
      bf16x8 bh = *(const bf16x8*)(cur + 8192 + (c * 64 + l) * 16);
      bf16x8 bl = *(const bf16x8*)(cur + 24576 + (c * 64 + l) * 16);
      acc[c] = __builtin_amdgcn_mfma_f32_16x16x32_bf16(ah, bh, acc[c], 0, 0, 0);
      acc[c] = __builtin_amdgcn_mfma_f32_16x16x32_bf16(al, bh, acc[c], 0, 0, 0);
      acc[c] = __builtin_amdgcn_mfma_f32_16x16x32_bf16(ah, bl, acc[c], 0, 0, 0);
    }
    __syncthreads();  // drain: next tile landed; all ds_reads of cur done
  }
  // store: C[w*16 + (l>>4)*4 + r][c*16 + (l&15)]
  int orow = row0 + w * 16 + (l >> 4) * 4;
#pragma unroll
  for (int r = 0; r < 4; ++r) {
    int rr = orow + r;
    if (rr < M) {
#pragma unroll
      for (int c = 0; c < 16; ++c)
        C[(size_t)rr * HH + c * 16 + (l & 15)] = acc[c][r];
    }
  }
}

// ---------------- CSR gather aggregate -> bf16 hi/lo output ----------------
// out = relu(sum_e wn[e]*h[col[e]] + di^2*h_i + b); one wave per node, lane = 4 feats.

__global__ __launch_bounds__(256) void aggregate_bf(const float* __restrict__ h,
                                                    const int* __restrict__ indptr,
                                                    const int* __restrict__ col,
                                                    const float* __restrict__ wn,
                                                    const float* __restrict__ dinv,
                                                    const float* __restrict__ bias,
                                                    ushortT* __restrict__ ohi,
                                                    ushortT* __restrict__ olo, int n) {
  int gw = (blockIdx.x * 256 + threadIdx.x) >> 6;
  int lane = threadIdx.x & 63;
  if (gw >= n) return;
  int beg = indptr[gw], end = indptr[gw + 1];
  float di = dinv[gw];
  float4 acc = make_float4(0.f, 0.f, 0.f, 0.f);
  int e = beg;
  for (; e + 8 <= end; e += 8) {
    int s0 = col[e], s1 = col[e + 1], s2 = col[e + 2], s3 = col[e + 3];
    int s4 = col[e + 4], s5 = col[e + 5], s6 = col[e + 6], s7 = col[e + 7];
    float w0 = wn[e], w1 = wn[e + 1], w2 = wn[e + 2], w3 = wn[e + 3];
    float w4 = wn[e + 4], w5 = wn[e + 5], w6 = wn[e + 6], w7 = wn[e + 7];
    float4 h0 = *(const float4*)(h + (size_t)s0 * HH + lane * 4);
    float4 h1 = *(const float4*)(h + (size_t)s1 * HH + lane * 4);
    float4 h2 = *(const float4*)(h + (size_t)s2 * HH + lane * 4);
    float4 h3 = *(const float4*)(h + (size_t)s3 * HH + lane * 4);
    float4 h4 = *(const float4*)(h + (size_t)s4 * HH + lane * 4);
    float4 h5 = *(const float4*)(h + (size_t)s5 * HH + lane * 4);
    float4 h6 = *(const float4*)(h + (size_t)s6 * HH + lane * 4);
    float4 h7 = *(const float4*)(h + (size_t)s7 * HH + lane * 4);
    acc.x += w0 * h0.x + w1 * h1.x + w2 * h2.x + w3 * h3.x + w4 * h4.x + w5 * h5.x + w6 * h6.x + w7 * h7.x;
    acc.y += w0 * h0.y + w1 * h1.y + w2 * h2.y + w3 * h3.y + w4 * h4.y + w5 * h5.y + w6 * h6.y + w7 * h7.y;
    acc.z += w0 * h0.z + w1 * h1.z + w2 * h2.z + w3 * h3.z + w4 * h4.z + w5 * h5.z + w6 * h6.z + w7 * h7.z;
    acc.w += w0 * h0.w + w1 * h1.w + w2 * h2.w + w3 * h3.w + w4 * h4.w + w5 * h5.w + w6 * h6.w + w7 * h7.w;
  }
  for (; e < end; ++e) {
    int s = col[e];
    float ws = wn[e];
    float4 hv = *(const float4*)(h + (size_t)s * HH + lane * 4);
    acc.x += ws * hv.x; acc.y += ws * hv.y; acc.z += ws * hv.z; acc.w += ws * hv.w;
  }
  float selfw = di * di;
  float4 hv = *(const float4*)(h + (size_t)gw * HH + lane * 4);
  acc.x += selfw * hv.x; acc.y += selfw * hv.y; acc.z += selfw * hv.z; acc.w += selfw * hv.w;
  const float4 bv = *(const float4*)(bias + lane * 4);
  float o0 = fmaxf(acc.x + bv.x, 0.f);
  float o1 = fmaxf(acc.y + bv.y, 0.f);
  float o2 = fmaxf(acc.z + bv.z, 0.f);
  float o3 = fmaxf(acc.w + bv.w, 0.f);
  ushort4 hvec, lvec;
  hvec.x = f2bf(o0); lvec.x = f2bf(o0 - bf2f(hvec.x));
  hvec.y = f2bf(o1); lvec.y = f2bf(o1 - bf2f(hvec.y));
  hvec.z = f2bf(o2); lvec.z = f2bf(o2 - bf2f(hvec.z));
  hvec.w = f2bf(o3); lvec.w = f2bf(o3 - bf2f(hvec.w));
  *(ushort4*)(ohi + (size_t)gw * HH + lane * 4) = hvec;
  *(ushort4*)(olo + (size_t)gw * HH + lane * 4) = lvec;
}

// ---------------- fused pair MLP (MFMA, double-buffered) ----------------
// A row p = concat(xl[y0[p]], xr[y1[p]]) [512]; hidden = relu(A@fcW + fcb); out = sigmoid(hidden.w2 + b2)

__device__ __forceinline__ void stage_mlp(const ushortT* __restrict__ XLhi,
                                          const ushortT* __restrict__ XLlo,
                                          const ushortT* __restrict__ XRhi,
                                          const ushortT* __restrict__ XRlo,
                                          const ushortT* __restrict__ Bhi,
                                          const ushortT* __restrict__ Blo,
                                          int nL, int nR,
                                          unsigned char* buf, int kt, int w, int l,
                                          int akg) {
  int k0 = kt * 32;
  const ushortT* shi;
  const ushortT* slo;
  int node, kk;
  if (kt < 8) { shi = XLhi; slo = XLlo; node = nL; kk = k0; }
  else        { shi = XRhi; slo = XRlo; node = nR; kk = k0 - 256; }
  size_t aoff = (size_t)node * HH + kk + akg * 8;
  gld16(shi + aoff, buf + w * 1024);
  gld16(slo + aoff, buf + 4096 + w * 1024);
  size_t bkoff = (size_t)akg * 8;
#pragma unroll
  for (int r = 0; r < 4; ++r) {
    int colc = (r * 4 + w) * 16 + (l & 15);
    size_t boff = (size_t)colc * 512 + k0 + bkoff;
    gld16(Bhi + boff, buf + 8192 + r * 4096 + w * 1024);
    gld16(Blo + boff, buf + 24576 + r * 4096 + w * 1024);
  }
}

__global__ __launch_bounds__(256) void mlp_mfma(const ushortT* __restrict__ XLhi,
                                                const ushortT* __restrict__ XLlo,
                                                const ushortT* __restrict__ XRhi,
                                                const ushortT* __restrict__ XRlo,
                                                const int* __restrict__ y,
                                                const ushortT* __restrict__ Bhi,
                                                const ushortT* __restrict__ Blo,
                                                const float* __restrict__ fcb,
                                                const float* __restrict__ w2,
                                                const float* __restrict__ b2,
                                                float* __restrict__ out, int P) {
  __shared__ __align__(16) unsigned char smem[81920];
  __shared__ int ynode[2][64];
  int tid = threadIdx.x;
  int w = tid >> 6, l = tid & 63;
  int p0 = blockIdx.x * 64;
  if (tid < 128) {
    int side = tid >> 6, r = tid & 63;
    int p = p0 + r;
    if (p >= P) p = P - 1;
    ynode[side][r] = y[2 * p + side];
  }
  __syncthreads();

  f32x4 acc[16];
#pragma unroll
  for (int c = 0; c < 16; ++c) acc[c] = (f32x4)(0.f);

  int arow = w * 16 + (l & 15);
  int akg = l >> 4;
  int nL = ynode[0][arow];
  int nR = ynode[1][arow];

  stage_mlp(XLhi, XLlo, XRhi, XRlo, Bhi, Blo, nL, nR, smem, 0, w, l, akg);
  __syncthreads();  // tile 0 ready

  for (int kt = 0; kt < 16; ++kt) {
    unsigned char* cur = smem + (kt & 1) * 40960;
    unsigned char* nxt = smem + ((kt & 1) ^ 1) * 40960;
    if (kt + 1 < 16)
      stage_mlp(XLhi, XLlo, XRhi, XRlo, Bhi, Blo, nL, nR, nxt, kt + 1, w, l, akg);
    bf16x8 ah = *(const bf16x8*)(cur + tid * 16);
    bf16x8 al = *(const bf16x8*)(cur + 4096 + tid * 16);
#pragma unroll
    for (int c = 0; c < 16; ++c) {
      bf16x8 bh = *(const bf16x8*)(cur + 8192 + (c * 64 + l) * 16);
      bf16x8 bl = *(const bf16x8*)(cur + 24576 + (c * 64 + l) * 16);
      acc[c] = __builtin_amdgcn_mfma_f32_16x16x32_bf16(ah, bh, acc[c], 0, 0, 0);
      acc[c] = __builtin_amdgcn_mfma_f32_16x16x32_bf16(al, bh, acc[c], 0, 0, 0);
      acc[c] = __builtin_amdgcn_mfma_f32_16x16x32_bf16(ah, bl, acc[c], 0, 0, 0);
    }
    __syncthreads();
  }
  // epilogue: bias+relu, dot w2 across cols; reduce over 16 lanes of each row group
  float part[4] = {0.f, 0.f, 0.f, 0.f};
  int cb = l & 15;
#pragma unroll
  for (int c = 0; c < 16; ++c) {
    int colc = c * 16 + cb;
    float bv = fcb[colc];
    float wv = w2[colc];
#pragma unroll
    for (int r = 0; r < 4; ++r) part[r] += fmaxf(acc[c][r] + bv, 0.f) * wv;
  }
  float bias2 = b2[0];
#pragma unroll
  for (int r = 0; r < 4; ++r) {
    float s = part[r];
    s += __shfl_xor(s, 1);
    s += __shfl_xor(s, 2);
    s += __shfl_xor(s, 4);
    s += __shfl_xor(s, 8);
    if ((l & 15) == 0) {
      int p = p0 + w * 16 + (l >> 4) * 4 + r;
      if (p < P) out[p] = 1.f / (1.f + expf(-(s + bias2)));
    }
  }
}

// ---------------- launch ----------------

extern "C" void kernel_launch(void* const* d_in, const int* in_sizes, int n_in,
                              void* d_out, int out_size, void* d_ws, size_t ws_size,
                              hipStream_t stream) {
  const float* x_s  = (const float*)d_in[0];
  const float* x_t  = (const float*)d_in[1];
  const int*   ei_s = (const int*)d_in[2];
  const int*   ei_t = (const int*)d_in[3];
  const int*   y    = (const int*)d_in[4];
  const float* W1   = (const float*)d_in[5];
  const float* b1   = (const float*)d_in[6];
  const float* W2   = (const float*)d_in[7];
  const float* b2   = (const float*)d_in[8];
  const float* fcW  = (const float*)d_in[9];
  const float* fcb  = (const float*)d_in[10];
  const float* fc2W = (const float*)d_in[11];
  const float* fc2b = (const float*)d_in[12];
  float* out = (float*)d_out;

  char* ws = (char*)d_ws;
  size_t off = 0;
  auto alloc = [&](size_t bytes) -> void* {
    void* p = ws + off;
    off += (bytes + 255) & ~(size_t)255;
    return p;
  };
  float* Hbuf      = (float*)alloc((size_t)NN * HH * 4);
  ushortT* tmp_hi  = (ushortT*)alloc((size_t)NN * HH * 2);
  ushortT* tmp_lo  = (ushortT*)alloc((size_t)NN * HH * 2);
  ushortT* xl_hi   = (ushortT*)alloc((size_t)NN * HH * 2);
  ushortT* xl_lo   = (ushortT*)alloc((size_t)NN * HH * 2);
  ushortT* xr_hi   = (ushortT*)alloc((size_t)NN * HH * 2);
  ushortT* xr_lo   = (ushortT*)alloc((size_t)NN * HH * 2);
  ushortT* xa_hi   = (ushortT*)alloc((size_t)NN * DIN * 2);
  ushortT* xa_lo   = (ushortT*)alloc((size_t)NN * DIN * 2);
  ushortT* W1t_hi  = (ushortT*)alloc((size_t)HH * DIN * 2);
  ushortT* W1t_lo  = (ushortT*)alloc((size_t)HH * DIN * 2);
  ushortT* W2t_hi  = (ushortT*)alloc((size_t)HH * HH * 2);
  ushortT* W2t_lo  = (ushortT*)alloc((size_t)HH * HH * 2);
  ushortT* fct_hi  = (ushortT*)alloc((size_t)HH * 512 * 2);
  ushortT* fct_lo  = (ushortT*)alloc((size_t)HH * 512 * 2);
  int* cnt_s    = (int*)alloc((size_t)NN * 4);
  int* cnt_t    = (int*)alloc((size_t)NN * 4);
  float* dinv_s = (float*)alloc((size_t)NN * 4);
  float* dinv_t = (float*)alloc((size_t)NN * 4);
  int* indptr_s = (int*)alloc((size_t)(NN + 1) * 4);
  int* indptr_t = (int*)alloc((size_t)(NN + 1) * 4);
  int* fill_s   = (int*)alloc((size_t)NN * 4);
  int* fill_t   = (int*)alloc((size_t)NN * 4);
  int* col_s    = (int*)alloc((size_t)EE * 4);
  int* col_t    = (int*)alloc((size_t)EE * 4);
  float* wn_s   = (float*)alloc((size_t)EE * 4);
  float* wn_t   = (float*)alloc((size_t)EE * 4);
  int* bsum     = (int*)alloc(1024 * 4);

  hipMemsetAsync(cnt_s, 0, (size_t)NN * 4, stream);
  hipMemsetAsync(cnt_t, 0, (size_t)NN * 4, stream);
  hipMemsetAsync(fill_s, 0, (size_t)NN * 4, stream);
  hipMemsetAsync(fill_t, 0, (size_t)NN * 4, stream);

  const int NB = (NN + 255) / 256;
  const int EB = (EE + 255) / 256;

  // weight splits (tiny)
  split_w_t<<<(DIN * HH + 255) / 256, 256, 0, stream>>>(W1, W1t_hi, W1t_lo, DIN);
  split_w_t<<<(HH * HH + 255) / 256, 256, 0, stream>>>(W2, W2t_hi, W2t_lo, HH);
  split_w_t<<<(512 * HH + 255) / 256, 256, 0, stream>>>(fcW, fct_hi, fct_lo, 512);

  // CSR for both graphs
  count_deg<<<EB, 256, 0, stream>>>(ei_s + EE, cnt_s, EE);
  compute_dinv<<<NB, 256, 0, stream>>>(cnt_s, dinv_s, NN);
  scan_block<<<NB, 256, 0, stream>>>(cnt_s, indptr_s, bsum, NN);
  scan_totals<<<1, 256, 0, stream>>>(bsum, NB);
  scan_add<<<NB, 256, 0, stream>>>(indptr_s, bsum, cnt_s, NN);
  fill_csr<<<EB, 256, 0, stream>>>(ei_s, ei_s + EE, indptr_s, dinv_s, fill_s, col_s, wn_s, EE);
  count_deg<<<EB, 256, 0, stream>>>(ei_t + EE, cnt_t, EE);
  compute_dinv<<<NB, 256, 0, stream>>>(cnt_t, dinv_t, NN);
  scan_block<<<NB, 256, 0, stream>>>(cnt_t, indptr_t, bsum, NN);
  scan_totals<<<1, 256, 0, stream>>>(bsum, NB);
  scan_add<<<NB, 256, 0, stream>>>(indptr_t, bsum, cnt_t, NN);
  fill_csr<<<EB, 256, 0, stream>>>(ei_t, ei_t + EE, indptr_t, dinv_t, fill_t, col_t, wn_t, EE);

  const int GB = (NN + 63) / 64;         // 782 gemm blocks
  const int AB = (NN * 64 + 255) / 256;  // aggregate: 1 wave/node
  const int XB = (NN * DIN / 4 + 255) / 256;

  // s tower
  split_x<<<XB, 256, 0, stream>>>(x_s, xa_hi, xa_lo, NN * DIN / 4);
  gemm_mfma<<<GB, 256, 0, stream>>>(xa_hi, xa_lo, W1t_hi, W1t_lo, Hbuf, NN, DIN);
  aggregate_bf<<<AB, 256, 0, stream>>>(Hbuf, indptr_s, col_s, wn_s, dinv_s, b1, tmp_hi, tmp_lo, NN);
  gemm_mfma<<<GB, 256, 0, stream>>>(tmp_hi, tmp_lo, W2t_hi, W2t_lo, Hbuf, NN, HH);
  aggregate_bf<<<AB, 256, 0, stream>>>(Hbuf, indptr_s, col_s, wn_s, dinv_s, b2, xl_hi, xl_lo, NN);
  // t tower
  split_x<<<XB, 256, 0, stream>>>(x_t, xa_hi, xa_lo, NN * DIN / 4);
  gemm_mfma<<<GB, 256, 0, stream>>>(xa_hi, xa_lo, W1t_hi, W1t_lo, Hbuf, NN, DIN);
  aggregate_bf<<<AB, 256, 0, stream>>>(Hbuf, indptr_t, col_t, wn_t, dinv_t, b1, tmp_hi, tmp_lo, NN);
  gemm_mfma<<<GB, 256, 0, stream>>>(tmp_hi, tmp_lo, W2t_hi, W2t_lo, Hbuf, NN, HH);
  aggregate_bf<<<AB, 256, 0, stream>>>(Hbuf, indptr_t, col_t, wn_t, dinv_t, b2, xr_hi, xr_lo, NN);
  // fused pair MLP
  mlp_mfma<<<(PP + 63) / 64, 256, 0, stream>>>(xl_hi, xl_lo, xr_hi, xr_lo, y,
                                               fct_hi, fct_lo, fcb, fc2W, fc2b, out, PP);
}

// Round 7
// 794.955 us; speedup vs baseline: 1.2012x; 1.2012x over previous
//
#include <hip/hip_runtime.h>
#include <math.h>

#define NN 50000
#define EE 500000
#define DIN 128
#define HH 256
#define PP 100000

typedef unsigned short ushortT;
typedef short bf16x8 __attribute__((ext_vector_type(8)));   // 8 bf16 in 4 VGPRs
typedef float f32x4 __attribute__((ext_vector_type(4)));

// ---- bf16 helpers (RNE) ----
__device__ __forceinline__ ushortT f2bf(float f) {
  unsigned u = __float_as_uint(f);
  unsigned r = u + 0x7FFFu + ((u >> 16) & 1u);
  return (ushortT)(r >> 16);
}
__device__ __forceinline__ float bf2f(ushortT h) {
  return __uint_as_float(((unsigned)h) << 16);
}

// async global->LDS, 16B per lane. LDS dest must be wave-uniform base (+lane*16 implicit).
__device__ __forceinline__ void gld16(const void* g, void* l) {
  __builtin_amdgcn_global_load_lds((const __attribute__((address_space(1))) void*)g,
                                   (__attribute__((address_space(3))) void*)l, 16, 0, 0);
}

// ---------------- CSR build ----------------

__global__ __launch_bounds__(256) void count_deg(const int* __restrict__ dst,
                                                 int* __restrict__ cnt, int n) {
  int i = blockIdx.x * 256 + threadIdx.x;
  if (i < n) atomicAdd(&cnt[dst[i]], 1);
}

__global__ __launch_bounds__(256) void compute_dinv(const int* __restrict__ cnt,
                                                    float* __restrict__ dinv, int n) {
  int i = blockIdx.x * 256 + threadIdx.x;
  if (i < n) dinv[i] = rsqrtf((float)(cnt[i] + 1));  // +1 self-loop
}

__global__ __launch_bounds__(256) void scan_block(const int* __restrict__ cnt,
                                                  int* __restrict__ outp,
                                                  int* __restrict__ bsum, int n) {
  __shared__ int s[256];
  int i = blockIdx.x * 256 + threadIdx.x;
  int v = (i < n) ? cnt[i] : 0;
  s[threadIdx.x] = v;
  __syncthreads();
  for (int off = 1; off < 256; off <<= 1) {
    int t = (threadIdx.x >= off) ? s[threadIdx.x - off] : 0;
    __syncthreads();
    s[threadIdx.x] += t;
    __syncthreads();
  }
  if (i < n) outp[i] = s[threadIdx.x] - v;
  if (threadIdx.x == 255) bsum[blockIdx.x] = s[255];
}

// parallel exclusive scan over <=256 block sums
__global__ __launch_bounds__(256) void scan_totals(int* __restrict__ bsum, int nb) {
  __shared__ int s[256];
  int t = threadIdx.x;
  int v = (t < nb) ? bsum[t] : 0;
  s[t] = v;
  __syncthreads();
  for (int off = 1; off < 256; off <<= 1) {
    int u = (t >= off) ? s[t - off] : 0;
    __syncthreads();
    s[t] += u;
    __syncthreads();
  }
  if (t < nb) bsum[t] = s[t] - v;  // exclusive
}

__global__ __launch_bounds__(256) void scan_add(int* __restrict__ indptr,
                                                const int* __restrict__ bsum,
                                                const int* __restrict__ cnt, int n) {
  int i = blockIdx.x * 256 + threadIdx.x;
  if (i < n) {
    int v = indptr[i] + bsum[blockIdx.x];
    indptr[i] = v;
    if (i == n - 1) indptr[n] = v + cnt[i];
  }
}

// fill CSR and precompute edge weight wn = dinv[src]*dinv[dst]
__global__ __launch_bounds__(256) void fill_csr(const int* __restrict__ src,
                                                const int* __restrict__ dst,
                                                const int* __restrict__ indptr,
                                                const float* __restrict__ dinv,
                                                int* __restrict__ fill,
                                                int* __restrict__ col,
                                                float* __restrict__ wn, int n) {
  int i = blockIdx.x * 256 + threadIdx.x;
  if (i < n) {
    int d = dst[i];
    int s = src[i];
    int p = atomicAdd(&fill[d], 1);
    int idx = indptr[d] + p;
    col[idx] = s;
    wn[idx] = dinv[s] * dinv[d];
  }
}

// ---------------- precision-split kernels ----------------

__global__ __launch_bounds__(256) void split_x(const float* __restrict__ x,
                                               ushortT* __restrict__ hi,
                                               ushortT* __restrict__ lo, int n4) {
  int i = blockIdx.x * 256 + threadIdx.x;
  if (i >= n4) return;
  float4 v = ((const float4*)x)[i];
  ushort4 h, l;
  h.x = f2bf(v.x); l.x = f2bf(v.x - bf2f(h.x));
  h.y = f2bf(v.y); l.y = f2bf(v.y - bf2f(h.y));
  h.z = f2bf(v.z); l.z = f2bf(v.z - bf2f(h.z));
  h.w = f2bf(v.w); l.w = f2bf(v.w - bf2f(h.w));
  ((ushort4*)hi)[i] = h;
  ((ushort4*)lo)[i] = l;
}

// W [K][256] fp32 -> Wt hi/lo [256][K] bf16 (transpose + split), tiny
__global__ __launch_bounds__(256) void split_w_t(const float* __restrict__ W,
                                                 ushortT* __restrict__ Whi,
                                                 ushortT* __restrict__ Wlo, int K) {
  int idx = blockIdx.x * 256 + threadIdx.x;
  if (idx >= K * 256) return;
  int k = idx >> 8, n = idx & 255;
  float v = W[idx];
  ushortT h = f2bf(v);
  Whi[(size_t)n * K + k] = h;
  Wlo[(size_t)n * K + k] = f2bf(v - bf2f(h));
}

// ---------------- MFMA GEMM (8 waves, single buffer): C[M][256] = A[M][K] @ Wt^T ----
// 512 threads = 8 waves; tile 128 rows x 256 cols; wave w owns rows w*16..w*16+15.
// K-chunk 32. LDS 48KB: Ahi[0,8K) Alo[8K,16K) Bhi[16K,32K) Blo[32K,48K).
// bf16x3: C = Ah*Bh + Al*Bh + Ah*Bl.

__global__ __launch_bounds__(512) void gemm_mfma(const ushortT* __restrict__ Ahi,
                                                 const ushortT* __restrict__ Alo,
                                                 const ushortT* __restrict__ Bhi,
                                                 const ushortT* __restrict__ Blo,
                                                 float* __restrict__ C, int M, int K) {
  __shared__ __align__(16) unsigned char smem[49152];
  int tid = threadIdx.x;
  int w = tid >> 6, l = tid & 63;
  int row0 = blockIdx.x * 128;

  f32x4 acc[16];
#pragma unroll
  for (int c = 0; c < 16; ++c) acc[c] = (f32x4)(0.f);

  int arow = w * 16 + (l & 15);
  int grow = row0 + arow;
  if (grow >= M) grow = M - 1;
  const size_t abase = (size_t)grow * K + (size_t)(l >> 4) * 8;
  size_t bkoff = (size_t)(l >> 4) * 8;

  for (int k0 = 0; k0 < K; k0 += 32) {
    gld16(Ahi + abase + k0, smem + w * 1024);
    gld16(Alo + abase + k0, smem + 8192 + w * 1024);
#pragma unroll
    for (int r = 0; r < 2; ++r) {
      int col = (r * 8 + w) * 16 + (l & 15);
      size_t boff = (size_t)col * K + k0 + bkoff;
      gld16(Bhi + boff, smem + 16384 + r * 8192 + w * 1024);
      gld16(Blo + boff, smem + 32768 + r * 8192 + w * 1024);
    }
    __syncthreads();  // drains vmcnt(0): tile ready
    bf16x8 ah = *(const bf16x8*)(smem + tid * 16);
    bf16x8 al = *(const bf16x8*)(smem + 8192 + tid * 16);
#pragma unroll
    for (int c = 0; c < 16; ++c) {
      bf16x8 bh = *(const bf16x8*)(smem + 16384 + (c * 64 + l) * 16);
      bf16x8 bl = *(const bf16x8*)(smem + 32768 + (c * 64 + l) * 16);
      acc[c] = __builtin_amdgcn_mfma_f32_16x16x32_bf16(ah, bh, acc[c], 0, 0, 0);
      acc[c] = __builtin_amdgcn_mfma_f32_16x16x32_bf16(al, bh, acc[c], 0, 0, 0);
      acc[c] = __builtin_amdgcn_mfma_f32_16x16x32_bf16(ah, bl, acc[c], 0, 0, 0);
    }
    __syncthreads();  // all ds_reads done before next stage overwrites
  }
  // store: C[w*16 + (l>>4)*4 + r][c*16 + (l&15)]
  int orow = row0 + w * 16 + (l >> 4) * 4;
#pragma unroll
  for (int r = 0; r < 4; ++r) {
    int rr = orow + r;
    if (rr < M) {
#pragma unroll
      for (int c = 0; c < 16; ++c)
        C[(size_t)rr * HH + c * 16 + (l & 15)] = acc[c][r];
    }
  }
}

// ---------------- CSR gather aggregate -> bf16 hi/lo output ----------------
// out = relu(sum_e wn[e]*h[col[e]] + di^2*h_i + b); one wave per node, lane = 4 feats.

__global__ __launch_bounds__(256) void aggregate_bf(const float* __restrict__ h,
                                                    const int* __restrict__ indptr,
                                                    const int* __restrict__ col,
                                                    const float* __restrict__ wn,
                                                    const float* __restrict__ dinv,
                                                    const float* __restrict__ bias,
                                                    ushortT* __restrict__ ohi,
                                                    ushortT* __restrict__ olo, int n) {
  int gw = (blockIdx.x * 256 + threadIdx.x) >> 6;
  int lane = threadIdx.x & 63;
  if (gw >= n) return;
  int beg = indptr[gw], end = indptr[gw + 1];
  float di = dinv[gw];
  float4 acc = make_float4(0.f, 0.f, 0.f, 0.f);
  int e = beg;
  for (; e + 8 <= end; e += 8) {
    int s0 = col[e], s1 = col[e + 1], s2 = col[e + 2], s3 = col[e + 3];
    int s4 = col[e + 4], s5 = col[e + 5], s6 = col[e + 6], s7 = col[e + 7];
    float w0 = wn[e], w1 = wn[e + 1], w2 = wn[e + 2], w3 = wn[e + 3];
    float w4 = wn[e + 4], w5 = wn[e + 5], w6 = wn[e + 6], w7 = wn[e + 7];
    float4 h0 = *(const float4*)(h + (size_t)s0 * HH + lane * 4);
    float4 h1 = *(const float4*)(h + (size_t)s1 * HH + lane * 4);
    float4 h2 = *(const float4*)(h + (size_t)s2 * HH + lane * 4);
    float4 h3 = *(const float4*)(h + (size_t)s3 * HH + lane * 4);
    float4 h4 = *(const float4*)(h + (size_t)s4 * HH + lane * 4);
    float4 h5 = *(const float4*)(h + (size_t)s5 * HH + lane * 4);
    float4 h6 = *(const float4*)(h + (size_t)s6 * HH + lane * 4);
    float4 h7 = *(const float4*)(h + (size_t)s7 * HH + lane * 4);
    acc.x += w0 * h0.x + w1 * h1.x + w2 * h2.x + w3 * h3.x + w4 * h4.x + w5 * h5.x + w6 * h6.x + w7 * h7.x;
    acc.y += w0 * h0.y + w1 * h1.y + w2 * h2.y + w3 * h3.y + w4 * h4.y + w5 * h5.y + w6 * h6.y + w7 * h7.y;
    acc.z += w0 * h0.z + w1 * h1.z + w2 * h2.z + w3 * h3.z + w4 * h4.z + w5 * h5.z + w6 * h6.z + w7 * h7.z;
    acc.w += w0 * h0.w + w1 * h1.w + w2 * h2.w + w3 * h3.w + w4 * h4.w + w5 * h5.w + w6 * h6.w + w7 * h7.w;
  }
  for (; e < end; ++e) {
    int s = col[e];
    float ws = wn[e];
    float4 hv = *(const float4*)(h + (size_t)s * HH + lane * 4);
    acc.x += ws * hv.x; acc.y += ws * hv.y; acc.z += ws * hv.z; acc.w += ws * hv.w;
  }
  float selfw = di * di;
  float4 hv = *(const float4*)(h + (size_t)gw * HH + lane * 4);
  acc.x += selfw * hv.x; acc.y += selfw * hv.y; acc.z += selfw * hv.z; acc.w += selfw * hv.w;
  const float4 bv = *(const float4*)(bias + lane * 4);
  float o0 = fmaxf(acc.x + bv.x, 0.f);
  float o1 = fmaxf(acc.y + bv.y, 0.f);
  float o2 = fmaxf(acc.z + bv.z, 0.f);
  float o3 = fmaxf(acc.w + bv.w, 0.f);
  ushort4 hvec, lvec;
  hvec.x = f2bf(o0); lvec.x = f2bf(o0 - bf2f(hvec.x));
  hvec.y = f2bf(o1); lvec.y = f2bf(o1 - bf2f(hvec.y));
  hvec.z = f2bf(o2); lvec.z = f2bf(o2 - bf2f(hvec.z));
  hvec.w = f2bf(o3); lvec.w = f2bf(o3 - bf2f(hvec.w));
  *(ushort4*)(ohi + (size_t)gw * HH + lane * 4) = hvec;
  *(ushort4*)(olo + (size_t)gw * HH + lane * 4) = lvec;
}

// ---------------- fused pair MLP (MFMA, 8 waves, single buffer) ----------------
// A row p = concat(xl[y0[p]], xr[y1[p]]) [512]; hidden = relu(A@fcW + fcb); out = sigmoid(hidden.w2 + b2)
// 512 threads; tile 128 pairs x 256 cols; LDS 48KB as in gemm_mfma, B has K=512.

__global__ __launch_bounds__(512) void mlp_mfma(const ushortT* __restrict__ XLhi,
                                                const ushortT* __restrict__ XLlo,
                                                const ushortT* __restrict__ XRhi,
                                                const ushortT* __restrict__ XRlo,
                                                const int* __restrict__ y,
                                                const ushortT* __restrict__ Bhi,
                                                const ushortT* __restrict__ Blo,
                                                const float* __restrict__ fcb,
                                                const float* __restrict__ w2,
                                                const float* __restrict__ b2,
                                                float* __restrict__ out, int P) {
  __shared__ __align__(16) unsigned char smem[49152];
  __shared__ int ynode[2][128];
  int tid = threadIdx.x;
  int w = tid >> 6, l = tid & 63;
  int p0 = blockIdx.x * 128;
  if (tid < 256) {
    int side = tid >> 7, r = tid & 127;
    int p = p0 + r;
    if (p >= P) p = P - 1;
    ynode[side][r] = y[2 * p + side];
  }
  __syncthreads();

  f32x4 acc[16];
#pragma unroll
  for (int c = 0; c < 16; ++c) acc[c] = (f32x4)(0.f);

  int arow = w * 16 + (l & 15);
  int akg = l >> 4;
  int nL = ynode[0][arow];
  int nR = ynode[1][arow];

  for (int kt = 0; kt < 16; ++kt) {
    int k0 = kt * 32;
    {
      const ushortT* shi;
      const ushortT* slo;
      int node, kk;
      if (kt < 8) { shi = XLhi; slo = XLlo; node = nL; kk = k0; }
      else        { shi = XRhi; slo = XRlo; node = nR; kk = k0 - 256; }
      size_t aoff = (size_t)node * HH + kk + akg * 8;
      gld16(shi + aoff, smem + w * 1024);
      gld16(slo + aoff, smem + 8192 + w * 1024);
      size_t bkoff = (size_t)akg * 8;
#pragma unroll
      for (int r = 0; r < 2; ++r) {
        int colc = (r * 8 + w) * 16 + (l & 15);
        size_t boff = (size_t)colc * 512 + k0 + bkoff;
        gld16(Bhi + boff, smem + 16384 + r * 8192 + w * 1024);
        gld16(Blo + boff, smem + 32768 + r * 8192 + w * 1024);
      }
    }
    __syncthreads();
    bf16x8 ah = *(const bf16x8*)(smem + tid * 16);
    bf16x8 al = *(const bf16x8*)(smem + 8192 + tid * 16);
#pragma unroll
    for (int c = 0; c < 16; ++c) {
      bf16x8 bh = *(const bf16x8*)(smem + 16384 + (c * 64 + l) * 16);
      bf16x8 bl = *(const bf16x8*)(smem + 32768 + (c * 64 + l) * 16);
      acc[c] = __builtin_amdgcn_mfma_f32_16x16x32_bf16(ah, bh, acc[c], 0, 0, 0);
      acc[c] = __builtin_amdgcn_mfma_f32_16x16x32_bf16(al, bh, acc[c], 0, 0, 0);
      acc[c] = __builtin_amdgcn_mfma_f32_16x16x32_bf16(ah, bl, acc[c], 0, 0, 0);
    }
    __syncthreads();
  }
  // epilogue: bias+relu, dot w2 across cols; reduce over 16 lanes of each row group
  float part[4] = {0.f, 0.f, 0.f, 0.f};
  int cb = l & 15;
#pragma unroll
  for (int c = 0; c < 16; ++c) {
    int colc = c * 16 + cb;
    float bv = fcb[colc];
    float wv = w2[colc];
#pragma unroll
    for (int r = 0; r < 4; ++r) part[r] += fmaxf(acc[c][r] + bv, 0.f) * wv;
  }
  float bias2 = b2[0];
#pragma unroll
  for (int r = 0; r < 4; ++r) {
    float s = part[r];
    s += __shfl_xor(s, 1);
    s += __shfl_xor(s, 2);
    s += __shfl_xor(s, 4);
    s += __shfl_xor(s, 8);
    if ((l & 15) == 0) {
      int p = p0 + w * 16 + (l >> 4) * 4 + r;
      if (p < P) out[p] = 1.f / (1.f + expf(-(s + bias2)));
    }
  }
}

// ---------------- launch ----------------

extern "C" void kernel_launch(void* const* d_in, const int* in_sizes, int n_in,
                              void* d_out, int out_size, void* d_ws, size_t ws_size,
                              hipStream_t stream) {
  const float* x_s  = (const float*)d_in[0];
  const float* x_t  = (const float*)d_in[1];
  const int*   ei_s = (const int*)d_in[2];
  const int*   ei_t = (const int*)d_in[3];
  const int*   y    = (const int*)d_in[4];
  const float* W1   = (const float*)d_in[5];
  const float* b1   = (const float*)d_in[6];
  const float* W2   = (const float*)d_in[7];
  const float* b2   = (const float*)d_in[8];
  const float* fcW  = (const float*)d_in[9];
  const float* fcb  = (const float*)d_in[10];
  const float* fc2W = (const float*)d_in[11];
  const float* fc2b = (const float*)d_in[12];
  float* out = (float*)d_out;

  char* ws = (char*)d_ws;
  size_t off = 0;
  auto alloc = [&](size_t bytes) -> void* {
    void* p = ws + off;
    off += (bytes + 255) & ~(size_t)255;
    return p;
  };
  float* Hbuf      = (float*)alloc((size_t)NN * HH * 4);
  ushortT* tmp_hi  = (ushortT*)alloc((size_t)NN * HH * 2);
  ushortT* tmp_lo  = (ushortT*)alloc((size_t)NN * HH * 2);
  ushortT* xl_hi   = (ushortT*)alloc((size_t)NN * HH * 2);
  ushortT* xl_lo   = (ushortT*)alloc((size_t)NN * HH * 2);
  ushortT* xr_hi   = (ushortT*)alloc((size_t)NN * HH * 2);
  ushortT* xr_lo   = (ushortT*)alloc((size_t)NN * HH * 2);
  ushortT* xa_hi   = (ushortT*)alloc((size_t)NN * DIN * 2);
  ushortT* xa_lo   = (ushortT*)alloc((size_t)NN * DIN * 2);
  ushortT* W1t_hi  = (ushortT*)alloc((size_t)HH * DIN * 2);
  ushortT* W1t_lo  = (ushortT*)alloc((size_t)HH * DIN * 2);
  ushortT* W2t_hi  = (ushortT*)alloc((size_t)HH * HH * 2);
  ushortT* W2t_lo  = (ushortT*)alloc((size_t)HH * HH * 2);
  ushortT* fct_hi  = (ushortT*)alloc((size_t)HH * 512 * 2);
  ushortT* fct_lo  = (ushortT*)alloc((size_t)HH * 512 * 2);
  int* cnt_s    = (int*)alloc((size_t)NN * 4);
  int* cnt_t    = (int*)alloc((size_t)NN * 4);
  float* dinv_s = (float*)alloc((size_t)NN * 4);
  float* dinv_t = (float*)alloc((size_t)NN * 4);
  int* indptr_s = (int*)alloc((size_t)(NN + 1) * 4);
  int* indptr_t = (int*)alloc((size_t)(NN + 1) * 4);
  int* fill_s   = (int*)alloc((size_t)NN * 4);
  int* fill_t   = (int*)alloc((size_t)NN * 4);
  int* col_s    = (int*)alloc((size_t)EE * 4);
  int* col_t    = (int*)alloc((size_t)EE * 4);
  float* wn_s   = (float*)alloc((size_t)EE * 4);
  float* wn_t   = (float*)alloc((size_t)EE * 4);
  int* bsum     = (int*)alloc(1024 * 4);

  hipMemsetAsync(cnt_s, 0, (size_t)NN * 4, stream);
  hipMemsetAsync(cnt_t, 0, (size_t)NN * 4, stream);
  hipMemsetAsync(fill_s, 0, (size_t)NN * 4, stream);
  hipMemsetAsync(fill_t, 0, (size_t)NN * 4, stream);

  const int NB = (NN + 255) / 256;
  const int EB = (EE + 255) / 256;

  // weight splits (tiny)
  split_w_t<<<(DIN * HH + 255) / 256, 256, 0, stream>>>(W1, W1t_hi, W1t_lo, DIN);
  split_w_t<<<(HH * HH + 255) / 256, 256, 0, stream>>>(W2, W2t_hi, W2t_lo, HH);
  split_w_t<<<(512 * HH + 255) / 256, 256, 0, stream>>>(fcW, fct_hi, fct_lo, 512);

  // CSR for both graphs
  count_deg<<<EB, 256, 0, stream>>>(ei_s + EE, cnt_s, EE);
  compute_dinv<<<NB, 256, 0, stream>>>(cnt_s, dinv_s, NN);
  scan_block<<<NB, 256, 0, stream>>>(cnt_s, indptr_s, bsum, NN);
  scan_totals<<<1, 256, 0, stream>>>(bsum, NB);
  scan_add<<<NB, 256, 0, stream>>>(indptr_s, bsum, cnt_s, NN);
  fill_csr<<<EB, 256, 0, stream>>>(ei_s, ei_s + EE, indptr_s, dinv_s, fill_s, col_s, wn_s, EE);
  count_deg<<<EB, 256, 0, stream>>>(ei_t + EE, cnt_t, EE);
  compute_dinv<<<NB, 256, 0, stream>>>(cnt_t, dinv_t, NN);
  scan_block<<<NB, 256, 0, stream>>>(cnt_t, indptr_t, bsum, NN);
  scan_totals<<<1, 256, 0, stream>>>(bsum, NB);
  scan_add<<<NB, 256, 0, stream>>>(indptr_t, bsum, cnt_t, NN);
  fill_csr<<<EB, 256, 0, stream>>>(ei_t, ei_t + EE, indptr_t, dinv_t, fill_t, col_t, wn_t, EE);

  const int GB = (NN + 127) / 128;       // 391 gemm blocks (128-row tile)
  const int AB = (NN * 64 + 255) / 256;  // aggregate: 1 wave/node
  const int XB = (NN * DIN / 4 + 255) / 256;

  // s tower
  split_x<<<XB, 256, 0, stream>>>(x_s, xa_hi, xa_lo, NN * DIN / 4);
  gemm_mfma<<<GB, 512, 0, stream>>>(xa_hi, xa_lo, W1t_hi, W1t_lo, Hbuf, NN, DIN);
  aggregate_bf<<<AB, 256, 0, stream>>>(Hbuf, indptr_s, col_s, wn_s, dinv_s, b1, tmp_hi, tmp_lo, NN);
  gemm_mfma<<<GB, 512, 0, stream>>>(tmp_hi, tmp_lo, W2t_hi, W2t_lo, Hbuf, NN, HH);
  aggregate_bf<<<AB, 256, 0, stream>>>(Hbuf, indptr_s, col_s, wn_s, dinv_s, b2, xl_hi, xl_lo, NN);
  // t tower
  split_x<<<XB, 256, 0, stream>>>(x_t, xa_hi, xa_lo, NN * DIN / 4);
  gemm_mfma<<<GB, 512, 0, stream>>>(xa_hi, xa_lo, W1t_hi, W1t_lo, Hbuf, NN, DIN);
  aggregate_bf<<<AB, 256, 0, stream>>>(Hbuf, indptr_t, col_t, wn_t, dinv_t, b1, tmp_hi, tmp_lo, NN);
  gemm_mfma<<<GB, 512, 0, stream>>>(tmp_hi, tmp_lo, W2t_hi, W2t_lo, Hbuf, NN, HH);
  aggregate_bf<<<AB, 256, 0, stream>>>(Hbuf, indptr_t, col_t, wn_t, dinv_t, b2, xr_hi, xr_lo, NN);
  // fused pair MLP (128 pairs per block)
  mlp_mfma<<<(PP + 127) / 128, 512, 0, stream>>>(xl_hi, xl_lo, xr_hi, xr_lo, y,
                                                 fct_hi, fct_lo, fcb, fc2W, fc2b, out, PP);
}

// Round 8
// 631.483 us; speedup vs baseline: 1.5122x; 1.2589x over previous
//
#include <hip/hip_runtime.h>
#include <math.h>

#define NN 50000
#define EE 500000
#define DIN 128
#define HH 256
#define PP 100000

typedef unsigned short ushortT;
typedef short bf16x8 __attribute__((ext_vector_type(8)));   // 8 bf16 in 4 VGPRs
typedef float f32x4 __attribute__((ext_vector_type(4)));

// ---- bf16 helpers (RNE) ----
__device__ __forceinline__ ushortT f2bf(float f) {
  unsigned u = __float_as_uint(f);
  unsigned r = u + 0x7FFFu + ((u >> 16) & 1u);
  return (ushortT)(r >> 16);
}
__device__ __forceinline__ float bf2f(ushortT h) {
  return __uint_as_float(((unsigned)h) << 16);
}

// async global->LDS, 16B per lane. LDS dest must be wave-uniform base (+lane*16 implicit).
__device__ __forceinline__ void gld16(const void* g, void* l) {
  __builtin_amdgcn_global_load_lds((const __attribute__((address_space(1))) void*)g,
                                   (__attribute__((address_space(3))) void*)l, 16, 0, 0);
}

// ---------------- CSR build ----------------

__global__ __launch_bounds__(256) void count_deg(const int* __restrict__ dst,
                                                 int* __restrict__ cnt, int n) {
  int i = blockIdx.x * 256 + threadIdx.x;
  if (i < n) atomicAdd(&cnt[dst[i]], 1);
}

__global__ __launch_bounds__(256) void compute_dinv(const int* __restrict__ cnt,
                                                    float* __restrict__ dinv, int n) {
  int i = blockIdx.x * 256 + threadIdx.x;
  if (i < n) dinv[i] = rsqrtf((float)(cnt[i] + 1));  // +1 self-loop
}

__global__ __launch_bounds__(256) void scan_block(const int* __restrict__ cnt,
                                                  int* __restrict__ outp,
                                                  int* __restrict__ bsum, int n) {
  __shared__ int s[256];
  int i = blockIdx.x * 256 + threadIdx.x;
  int v = (i < n) ? cnt[i] : 0;
  s[threadIdx.x] = v;
  __syncthreads();
  for (int off = 1; off < 256; off <<= 1) {
    int t = (threadIdx.x >= off) ? s[threadIdx.x - off] : 0;
    __syncthreads();
    s[threadIdx.x] += t;
    __syncthreads();
  }
  if (i < n) outp[i] = s[threadIdx.x] - v;
  if (threadIdx.x == 255) bsum[blockIdx.x] = s[255];
}

// parallel exclusive scan over <=256 block sums
__global__ __launch_bounds__(256) void scan_totals(int* __restrict__ bsum, int nb) {
  __shared__ int s[256];
  int t = threadIdx.x;
  int v = (t < nb) ? bsum[t] : 0;
  s[t] = v;
  __syncthreads();
  for (int off = 1; off < 256; off <<= 1) {
    int u = (t >= off) ? s[t - off] : 0;
    __syncthreads();
    s[t] += u;
    __syncthreads();
  }
  if (t < nb) bsum[t] = s[t] - v;  // exclusive
}

__global__ __launch_bounds__(256) void scan_add(int* __restrict__ indptr,
                                                const int* __restrict__ bsum,
                                                const int* __restrict__ cnt, int n) {
  int i = blockIdx.x * 256 + threadIdx.x;
  if (i < n) {
    int v = indptr[i] + bsum[blockIdx.x];
    indptr[i] = v;
    if (i == n - 1) indptr[n] = v + cnt[i];
  }
}

// fill CSR and precompute edge weight wn = dinv[src]*dinv[dst]
__global__ __launch_bounds__(256) void fill_csr(const int* __restrict__ src,
                                                const int* __restrict__ dst,
                                                const int* __restrict__ indptr,
                                                const float* __restrict__ dinv,
                                                int* __restrict__ fill,
                                                int* __restrict__ col,
                                                float* __restrict__ wn, int n) {
  int i = blockIdx.x * 256 + threadIdx.x;
  if (i < n) {
    int d = dst[i];
    int s = src[i];
    int p = atomicAdd(&fill[d], 1);
    int idx = indptr[d] + p;
    col[idx] = s;
    wn[idx] = dinv[s] * dinv[d];
  }
}

// ---------------- precision-split kernels ----------------

__global__ __launch_bounds__(256) void split_x(const float* __restrict__ x,
                                               ushortT* __restrict__ hi,
                                               ushortT* __restrict__ lo, int n4) {
  int i = blockIdx.x * 256 + threadIdx.x;
  if (i >= n4) return;
  float4 v = ((const float4*)x)[i];
  ushort4 h, l;
  h.x = f2bf(v.x); l.x = f2bf(v.x - bf2f(h.x));
  h.y = f2bf(v.y); l.y = f2bf(v.y - bf2f(h.y));
  h.z = f2bf(v.z); l.z = f2bf(v.z - bf2f(h.z));
  h.w = f2bf(v.w); l.w = f2bf(v.w - bf2f(h.w));
  ((ushort4*)hi)[i] = h;
  ((ushort4*)lo)[i] = l;
}

// W [K][256] fp32 -> Wt hi/lo [256][K] bf16 (transpose + split), tiny
__global__ __launch_bounds__(256) void split_w_t(const float* __restrict__ W,
                                                 ushortT* __restrict__ Whi,
                                                 ushortT* __restrict__ Wlo, int K) {
  int idx = blockIdx.x * 256 + threadIdx.x;
  if (idx >= K * 256) return;
  int k = idx >> 8, n = idx & 255;
  float v = W[idx];
  ushortT h = f2bf(v);
  Whi[(size_t)n * K + k] = h;
  Wlo[(size_t)n * K + k] = f2bf(v - bf2f(h));
}

// ---------------- MFMA GEMM (8 waves, single buffer): C[M][256] = A[M][K] @ Wt^T ----
// 512 threads = 8 waves; tile 128 rows x 256 cols. K-chunk 32.
// LDS 48KB: Ahi[0,8K) Alo[8K,16K) Bhi[16K,32K) Blo[32K,48K).
// bf16x3: C = Ah*Bh + Al*Bh + Ah*Bl. Output written as bf16 (hi only).

__global__ __launch_bounds__(512) void gemm_mfma(const ushortT* __restrict__ Ahi,
                                                 const ushortT* __restrict__ Alo,
                                                 const ushortT* __restrict__ Bhi,
                                                 const ushortT* __restrict__ Blo,
                                                 ushortT* __restrict__ C, int M, int K) {
  __shared__ __align__(16) unsigned char smem[49152];
  int tid = threadIdx.x;
  int w = tid >> 6, l = tid & 63;
  int row0 = blockIdx.x * 128;

  f32x4 acc[16];
#pragma unroll
  for (int c = 0; c < 16; ++c) acc[c] = (f32x4)(0.f);

  int arow = w * 16 + (l & 15);
  int grow = row0 + arow;
  if (grow >= M) grow = M - 1;
  const size_t abase = (size_t)grow * K + (size_t)(l >> 4) * 8;
  size_t bkoff = (size_t)(l >> 4) * 8;

  for (int k0 = 0; k0 < K; k0 += 32) {
    gld16(Ahi + abase + k0, smem + w * 1024);
    gld16(Alo + abase + k0, smem + 8192 + w * 1024);
#pragma unroll
    for (int r = 0; r < 2; ++r) {
      int col = (r * 8 + w) * 16 + (l & 15);
      size_t boff = (size_t)col * K + k0 + bkoff;
      gld16(Bhi + boff, smem + 16384 + r * 8192 + w * 1024);
      gld16(Blo + boff, smem + 32768 + r * 8192 + w * 1024);
    }
    __syncthreads();  // drains vmcnt(0): tile ready
    bf16x8 ah = *(const bf16x8*)(smem + tid * 16);
    bf16x8 al = *(const bf16x8*)(smem + 8192 + tid * 16);
#pragma unroll
    for (int c = 0; c < 16; ++c) {
      bf16x8 bh = *(const bf16x8*)(smem + 16384 + (c * 64 + l) * 16);
      bf16x8 bl = *(const bf16x8*)(smem + 32768 + (c * 64 + l) * 16);
      acc[c] = __builtin_amdgcn_mfma_f32_16x16x32_bf16(ah, bh, acc[c], 0, 0, 0);
      acc[c] = __builtin_amdgcn_mfma_f32_16x16x32_bf16(al, bh, acc[c], 0, 0, 0);
      acc[c] = __builtin_amdgcn_mfma_f32_16x16x32_bf16(ah, bl, acc[c], 0, 0, 0);
    }
    __syncthreads();  // all ds_reads done before next stage overwrites
  }
  // store bf16: C[w*16 + (l>>4)*4 + r][c*16 + (l&15)]
  int orow = row0 + w * 16 + (l >> 4) * 4;
#pragma unroll
  for (int r = 0; r < 4; ++r) {
    int rr = orow + r;
    if (rr < M) {
#pragma unroll
      for (int c = 0; c < 16; ++c)
        C[(size_t)rr * HH + c * 16 + (l & 15)] = f2bf(acc[c][r]);
    }
  }
}

// ---------------- CSR gather aggregate (bf16 h rows) -> bf16 hi[/lo] output ----
// out = relu(sum_e wn[e]*h[col[e]] + di^2*h_i + b); one wave per node, lane = 4 feats (8B).

__global__ __launch_bounds__(256) void aggregate_bf(const ushortT* __restrict__ h,
                                                    const int* __restrict__ indptr,
                                                    const int* __restrict__ col,
                                                    const float* __restrict__ wn,
                                                    const float* __restrict__ dinv,
                                                    const float* __restrict__ bias,
                                                    ushortT* __restrict__ ohi,
                                                    ushortT* __restrict__ olo,
                                                    int n, int writeLo) {
  int gw = (blockIdx.x * 256 + threadIdx.x) >> 6;
  int lane = threadIdx.x & 63;
  if (gw >= n) return;
  int beg = indptr[gw], end = indptr[gw + 1];
  float di = dinv[gw];
  float4 acc = make_float4(0.f, 0.f, 0.f, 0.f);
  int e = beg;
  for (; e + 8 <= end; e += 8) {
    int s0 = col[e], s1 = col[e + 1], s2 = col[e + 2], s3 = col[e + 3];
    int s4 = col[e + 4], s5 = col[e + 5], s6 = col[e + 6], s7 = col[e + 7];
    float w0 = wn[e], w1 = wn[e + 1], w2 = wn[e + 2], w3 = wn[e + 3];
    float w4 = wn[e + 4], w5 = wn[e + 5], w6 = wn[e + 6], w7 = wn[e + 7];
    ushort4 r0 = *(const ushort4*)(h + (size_t)s0 * HH + lane * 4);
    ushort4 r1 = *(const ushort4*)(h + (size_t)s1 * HH + lane * 4);
    ushort4 r2 = *(const ushort4*)(h + (size_t)s2 * HH + lane * 4);
    ushort4 r3 = *(const ushort4*)(h + (size_t)s3 * HH + lane * 4);
    ushort4 r4 = *(const ushort4*)(h + (size_t)s4 * HH + lane * 4);
    ushort4 r5 = *(const ushort4*)(h + (size_t)s5 * HH + lane * 4);
    ushort4 r6 = *(const ushort4*)(h + (size_t)s6 * HH + lane * 4);
    ushort4 r7 = *(const ushort4*)(h + (size_t)s7 * HH + lane * 4);
    acc.x += w0 * bf2f(r0.x) + w1 * bf2f(r1.x) + w2 * bf2f(r2.x) + w3 * bf2f(r3.x)
           + w4 * bf2f(r4.x) + w5 * bf2f(r5.x) + w6 * bf2f(r6.x) + w7 * bf2f(r7.x);
    acc.y += w0 * bf2f(r0.y) + w1 * bf2f(r1.y) + w2 * bf2f(r2.y) + w3 * bf2f(r3.y)
           + w4 * bf2f(r4.y) + w5 * bf2f(r5.y) + w6 * bf2f(r6.y) + w7 * bf2f(r7.y);
    acc.z += w0 * bf2f(r0.z) + w1 * bf2f(r1.z) + w2 * bf2f(r2.z) + w3 * bf2f(r3.z)
           + w4 * bf2f(r4.z) + w5 * bf2f(r5.z) + w6 * bf2f(r6.z) + w7 * bf2f(r7.z);
    acc.w += w0 * bf2f(r0.w) + w1 * bf2f(r1.w) + w2 * bf2f(r2.w) + w3 * bf2f(r3.w)
           + w4 * bf2f(r4.w) + w5 * bf2f(r5.w) + w6 * bf2f(r6.w) + w7 * bf2f(r7.w);
  }
  for (; e < end; ++e) {
    int s = col[e];
    float ws = wn[e];
    ushort4 rv = *(const ushort4*)(h + (size_t)s * HH + lane * 4);
    acc.x += ws * bf2f(rv.x); acc.y += ws * bf2f(rv.y);
    acc.z += ws * bf2f(rv.z); acc.w += ws * bf2f(rv.w);
  }
  float selfw = di * di;
  ushort4 sv = *(const ushort4*)(h + (size_t)gw * HH + lane * 4);
  acc.x += selfw * bf2f(sv.x); acc.y += selfw * bf2f(sv.y);
  acc.z += selfw * bf2f(sv.z); acc.w += selfw * bf2f(sv.w);
  const float4 bv = *(const float4*)(bias + lane * 4);
  float o0 = fmaxf(acc.x + bv.x, 0.f);
  float o1 = fmaxf(acc.y + bv.y, 0.f);
  float o2 = fmaxf(acc.z + bv.z, 0.f);
  float o3 = fmaxf(acc.w + bv.w, 0.f);
  ushort4 hvec;
  hvec.x = f2bf(o0); hvec.y = f2bf(o1); hvec.z = f2bf(o2); hvec.w = f2bf(o3);
  *(ushort4*)(ohi + (size_t)gw * HH + lane * 4) = hvec;
  if (writeLo) {
    ushort4 lvec;
    lvec.x = f2bf(o0 - bf2f(hvec.x));
    lvec.y = f2bf(o1 - bf2f(hvec.y));
    lvec.z = f2bf(o2 - bf2f(hvec.z));
    lvec.w = f2bf(o3 - bf2f(hvec.w));
    *(ushort4*)(olo + (size_t)gw * HH + lane * 4) = lvec;
  }
}

// ---------------- fused pair MLP (MFMA, 8 waves; A hi-only, B hi/lo) ----------------
// A row p = concat(xl[y0[p]], xr[y1[p]]) [512]; hidden = relu(A@fcW + fcb); out = sigmoid(hidden.w2 + b2)
// 512 threads; tile 128 pairs x 256 cols; LDS 40KB: A[0,8K) Bhi[8K,24K) Blo[24K,40K).

__global__ __launch_bounds__(512) void mlp_mfma(const ushortT* __restrict__ XLhi,
                                                const ushortT* __restrict__ XRhi,
                                                const int* __restrict__ y,
                                                const ushortT* __restrict__ Bhi,
                                                const ushortT* __restrict__ Blo,
                                                const float* __restrict__ fcb,
                                                const float* __restrict__ w2,
                                                const float* __restrict__ b2,
                                                float* __restrict__ out, int P) {
  __shared__ __align__(16) unsigned char smem[40960];
  __shared__ int ynode[2][128];
  int tid = threadIdx.x;
  int w = tid >> 6, l = tid & 63;
  int p0 = blockIdx.x * 128;
  if (tid < 256) {
    int side = tid >> 7, r = tid & 127;
    int p = p0 + r;
    if (p >= P) p = P - 1;
    ynode[side][r] = y[2 * p + side];
  }
  __syncthreads();

  f32x4 acc[16];
#pragma unroll
  for (int c = 0; c < 16; ++c) acc[c] = (f32x4)(0.f);

  int arow = w * 16 + (l & 15);
  int akg = l >> 4;
  int nL = ynode[0][arow];
  int nR = ynode[1][arow];

  for (int kt = 0; kt < 16; ++kt) {
    int k0 = kt * 32;
    {
      const ushortT* shi = (kt < 8) ? XLhi : XRhi;
      int node = (kt < 8) ? nL : nR;
      int kk = (kt < 8) ? k0 : k0 - 256;
      size_t aoff = (size_t)node * HH + kk + akg * 8;
      gld16(shi + aoff, smem + w * 1024);
      size_t bkoff = (size_t)akg * 8;
#pragma unroll
      for (int r = 0; r < 2; ++r) {
        int colc = (r * 8 + w) * 16 + (l & 15);
        size_t boff = (size_t)colc * 512 + k0 + bkoff;
        gld16(Bhi + boff, smem + 8192 + r * 8192 + w * 1024);
        gld16(Blo + boff, smem + 24576 + r * 8192 + w * 1024);
      }
    }
    __syncthreads();
    bf16x8 ah = *(const bf16x8*)(smem + tid * 16);
#pragma unroll
    for (int c = 0; c < 16; ++c) {
      bf16x8 bh = *(const bf16x8*)(smem + 8192 + (c * 64 + l) * 16);
      bf16x8 bl = *(const bf16x8*)(smem + 24576 + (c * 64 + l) * 16);
      acc[c] = __builtin_amdgcn_mfma_f32_16x16x32_bf16(ah, bh, acc[c], 0, 0, 0);
      acc[c] = __builtin_amdgcn_mfma_f32_16x16x32_bf16(ah, bl, acc[c], 0, 0, 0);
    }
    __syncthreads();
  }
  // epilogue: bias+relu, dot w2 across cols; reduce over 16 lanes of each row group
  float part[4] = {0.f, 0.f, 0.f, 0.f};
  int cb = l & 15;
#pragma unroll
  for (int c = 0; c < 16; ++c) {
    int colc = c * 16 + cb;
    float bv = fcb[colc];
    float wv = w2[colc];
#pragma unroll
    for (int r = 0; r < 4; ++r) part[r] += fmaxf(acc[c][r] + bv, 0.f) * wv;
  }
  float bias2 = b2[0];
#pragma unroll
  for (int r = 0; r < 4; ++r) {
    float s = part[r];
    s += __shfl_xor(s, 1);
    s += __shfl_xor(s, 2);
    s += __shfl_xor(s, 4);
    s += __shfl_xor(s, 8);
    if ((l & 15) == 0) {
      int p = p0 + w * 16 + (l >> 4) * 4 + r;
      if (p < P) out[p] = 1.f / (1.f + expf(-(s + bias2)));
    }
  }
}

// ---------------- launch ----------------

extern "C" void kernel_launch(void* const* d_in, const int* in_sizes, int n_in,
                              void* d_out, int out_size, void* d_ws, size_t ws_size,
                              hipStream_t stream) {
  const float* x_s  = (const float*)d_in[0];
  const float* x_t  = (const float*)d_in[1];
  const int*   ei_s = (const int*)d_in[2];
  const int*   ei_t = (const int*)d_in[3];
  const int*   y    = (const int*)d_in[4];
  const float* W1   = (const float*)d_in[5];
  const float* b1   = (const float*)d_in[6];
  const float* W2   = (const float*)d_in[7];
  const float* b2   = (const float*)d_in[8];
  const float* fcW  = (const float*)d_in[9];
  const float* fcb  = (const float*)d_in[10];
  const float* fc2W = (const float*)d_in[11];
  const float* fc2b = (const float*)d_in[12];
  float* out = (float*)d_out;

  char* ws = (char*)d_ws;
  size_t off = 0;
  auto alloc = [&](size_t bytes) -> void* {
    void* p = ws + off;
    off += (bytes + 255) & ~(size_t)255;
    return p;
  };
  ushortT* hb_bf   = (ushortT*)alloc((size_t)NN * HH * 2);  // GEMM output (bf16 hi)
  ushortT* tmp_hi  = (ushortT*)alloc((size_t)NN * HH * 2);
  ushortT* tmp_lo  = (ushortT*)alloc((size_t)NN * HH * 2);
  ushortT* xl_hi   = (ushortT*)alloc((size_t)NN * HH * 2);
  ushortT* xr_hi   = (ushortT*)alloc((size_t)NN * HH * 2);
  ushortT* xa_hi   = (ushortT*)alloc((size_t)NN * DIN * 2);
  ushortT* xa_lo   = (ushortT*)alloc((size_t)NN * DIN * 2);
  ushortT* W1t_hi  = (ushortT*)alloc((size_t)HH * DIN * 2);
  ushortT* W1t_lo  = (ushortT*)alloc((size_t)HH * DIN * 2);
  ushortT* W2t_hi  = (ushortT*)alloc((size_t)HH * HH * 2);
  ushortT* W2t_lo  = (ushortT*)alloc((size_t)HH * HH * 2);
  ushortT* fct_hi  = (ushortT*)alloc((size_t)HH * 512 * 2);
  ushortT* fct_lo  = (ushortT*)alloc((size_t)HH * 512 * 2);
  int* cnt_s    = (int*)alloc((size_t)NN * 4);
  int* cnt_t    = (int*)alloc((size_t)NN * 4);
  float* dinv_s = (float*)alloc((size_t)NN * 4);
  float* dinv_t = (float*)alloc((size_t)NN * 4);
  int* indptr_s = (int*)alloc((size_t)(NN + 1) * 4);
  int* indptr_t = (int*)alloc((size_t)(NN + 1) * 4);
  int* fill_s   = (int*)alloc((size_t)NN * 4);
  int* fill_t   = (int*)alloc((size_t)NN * 4);
  int* col_s    = (int*)alloc((size_t)EE * 4);
  int* col_t    = (int*)alloc((size_t)EE * 4);
  float* wn_s   = (float*)alloc((size_t)EE * 4);
  float* wn_t   = (float*)alloc((size_t)EE * 4);
  int* bsum     = (int*)alloc(1024 * 4);

  hipMemsetAsync(cnt_s, 0, (size_t)NN * 4, stream);
  hipMemsetAsync(cnt_t, 0, (size_t)NN * 4, stream);
  hipMemsetAsync(fill_s, 0, (size_t)NN * 4, stream);
  hipMemsetAsync(fill_t, 0, (size_t)NN * 4, stream);

  const int NB = (NN + 255) / 256;
  const int EB = (EE + 255) / 256;

  // weight splits (tiny)
  split_w_t<<<(DIN * HH + 255) / 256, 256, 0, stream>>>(W1, W1t_hi, W1t_lo, DIN);
  split_w_t<<<(HH * HH + 255) / 256, 256, 0, stream>>>(W2, W2t_hi, W2t_lo, HH);
  split_w_t<<<(512 * HH + 255) / 256, 256, 0, stream>>>(fcW, fct_hi, fct_lo, 512);

  // CSR for both graphs
  count_deg<<<EB, 256, 0, stream>>>(ei_s + EE, cnt_s, EE);
  compute_dinv<<<NB, 256, 0, stream>>>(cnt_s, dinv_s, NN);
  scan_block<<<NB, 256, 0, stream>>>(cnt_s, indptr_s, bsum, NN);
  scan_totals<<<1, 256, 0, stream>>>(bsum, NB);
  scan_add<<<NB, 256, 0, stream>>>(indptr_s, bsum, cnt_s, NN);
  fill_csr<<<EB, 256, 0, stream>>>(ei_s, ei_s + EE, indptr_s, dinv_s, fill_s, col_s, wn_s, EE);
  count_deg<<<EB, 256, 0, stream>>>(ei_t + EE, cnt_t, EE);
  compute_dinv<<<NB, 256, 0, stream>>>(cnt_t, dinv_t, NN);
  scan_block<<<NB, 256, 0, stream>>>(cnt_t, indptr_t, bsum, NN);
  scan_totals<<<1, 256, 0, stream>>>(bsum, NB);
  scan_add<<<NB, 256, 0, stream>>>(indptr_t, bsum, cnt_t, NN);
  fill_csr<<<EB, 256, 0, stream>>>(ei_t, ei_t + EE, indptr_t, dinv_t, fill_t, col_t, wn_t, EE);

  const int GB = (NN + 127) / 128;       // 391 gemm blocks (128-row tile)
  const int AB = (NN * 64 + 255) / 256;  // aggregate: 1 wave/node
  const int XB = (NN * DIN / 4 + 255) / 256;

  // s tower
  split_x<<<XB, 256, 0, stream>>>(x_s, xa_hi, xa_lo, NN * DIN / 4);
  gemm_mfma<<<GB, 512, 0, stream>>>(xa_hi, xa_lo, W1t_hi, W1t_lo, hb_bf, NN, DIN);
  aggregate_bf<<<AB, 256, 0, stream>>>(hb_bf, indptr_s, col_s, wn_s, dinv_s, b1, tmp_hi, tmp_lo, NN, 1);
  gemm_mfma<<<GB, 512, 0, stream>>>(tmp_hi, tmp_lo, W2t_hi, W2t_lo, hb_bf, NN, HH);
  aggregate_bf<<<AB, 256, 0, stream>>>(hb_bf, indptr_s, col_s, wn_s, dinv_s, b2, xl_hi, xl_hi, NN, 0);
  // t tower
  split_x<<<XB, 256, 0, stream>>>(x_t, xa_hi, xa_lo, NN * DIN / 4);
  gemm_mfma<<<GB, 512, 0, stream>>>(xa_hi, xa_lo, W1t_hi, W1t_lo, hb_bf, NN, DIN);
  aggregate_bf<<<AB, 256, 0, stream>>>(hb_bf, indptr_t, col_t, wn_t, dinv_t, b1, tmp_hi, tmp_lo, NN, 1);
  gemm_mfma<<<GB, 512, 0, stream>>>(tmp_hi, tmp_lo, W2t_hi, W2t_lo, hb_bf, NN, HH);
  aggregate_bf<<<AB, 256, 0, stream>>>(hb_bf, indptr_t, col_t, wn_t, dinv_t, b2, xr_hi, xr_hi, NN, 0);
  // fused pair MLP (128 pairs per block; A hi-only)
  mlp_mfma<<<(PP + 127) / 128, 512, 0, stream>>>(xl_hi, xr_hi, y,
                                                 fct_hi, fct_lo, fcb, fc2W, fc2b, out, PP);
}

// Round 10
// 593.457 us; speedup vs baseline: 1.6091x; 1.0641x over previous
//
#include <hip/hip_runtime.h>
#include <math.h>

#define NN 50000
#define NN2 100000          // both towers batched
#define EE 500000
#define EE2 1000000
#define DIN 128
#define HH 256
#define PP 100000

typedef unsigned short ushortT;
typedef short bf16x8 __attribute__((ext_vector_type(8)));   // 8 bf16 in 4 VGPRs
typedef float f32x4 __attribute__((ext_vector_type(4)));

// ---- bf16 helpers (RNE) ----
__device__ __forceinline__ ushortT f2bf(float f) {
  unsigned u = __float_as_uint(f);
  unsigned r = u + 0x7FFFu + ((u >> 16) & 1u);
  return (ushortT)(r >> 16);
}
__device__ __forceinline__ float bf2f(ushortT h) {
  return __uint_as_float(((unsigned)h) << 16);
}

// async global->LDS, 16B per lane. LDS dest must be wave-uniform base (+lane*16 implicit).
__device__ __forceinline__ void gld16(const void* g, void* l) {
  __builtin_amdgcn_global_load_lds((const __attribute__((address_space(1))) void*)g,
                                   (__attribute__((address_space(3))) void*)l, 16, 0, 0);
}

// ---------------- batched CSR build (both graphs; t-nodes offset +NN) ----------------

__global__ __launch_bounds__(256) void count_deg2(const int* __restrict__ dst_s,
                                                  const int* __restrict__ dst_t,
                                                  int* __restrict__ cnt) {
  int i = blockIdx.x * 256 + threadIdx.x;
  if (i < EE) atomicAdd(&cnt[dst_s[i]], 1);
  else if (i < EE2) atomicAdd(&cnt[dst_t[i - EE] + NN], 1);
}

__global__ __launch_bounds__(256) void compute_dinv(const int* __restrict__ cnt,
                                                    float* __restrict__ dinv, int n) {
  int i = blockIdx.x * 256 + threadIdx.x;
  if (i < n) dinv[i] = rsqrtf((float)(cnt[i] + 1));  // +1 self-loop
}

__global__ __launch_bounds__(256) void scan_block(const int* __restrict__ cnt,
                                                  int* __restrict__ outp,
                                                  int* __restrict__ bsum, int n) {
  __shared__ int s[256];
  int i = blockIdx.x * 256 + threadIdx.x;
  int v = (i < n) ? cnt[i] : 0;
  s[threadIdx.x] = v;
  __syncthreads();
  for (int off = 1; off < 256; off <<= 1) {
    int t = (threadIdx.x >= off) ? s[threadIdx.x - off] : 0;
    __syncthreads();
    s[threadIdx.x] += t;
    __syncthreads();
  }
  if (i < n) outp[i] = s[threadIdx.x] - v;
  if (threadIdx.x == 255) bsum[blockIdx.x] = s[255];
}

// parallel exclusive scan over <=512 block sums
__global__ __launch_bounds__(512) void scan_totals(int* __restrict__ bsum, int nb) {
  __shared__ int s[512];
  int t = threadIdx.x;
  int v = (t < nb) ? bsum[t] : 0;
  s[t] = v;
  __syncthreads();
  for (int off = 1; off < 512; off <<= 1) {
    int u = (t >= off) ? s[t - off] : 0;
    __syncthreads();
    s[t] += u;
    __syncthreads();
  }
  if (t < nb) bsum[t] = s[t] - v;  // exclusive
}

__global__ __launch_bounds__(256) void scan_add(int* __restrict__ indptr,
                                                const int* __restrict__ bsum,
                                                const int* __restrict__ cnt, int n) {
  int i = blockIdx.x * 256 + threadIdx.x;
  if (i < n) {
    int v = indptr[i] + bsum[blockIdx.x];
    indptr[i] = v;
    if (i == n - 1) indptr[n] = v + cnt[i];
  }
}

// fill batched CSR and precompute edge weight wn = dinv[src]*dinv[dst]
__global__ __launch_bounds__(256) void fill_csr2(const int* __restrict__ ei_s,
                                                 const int* __restrict__ ei_t,
                                                 const int* __restrict__ indptr,
                                                 const float* __restrict__ dinv,
                                                 int* __restrict__ fill,
                                                 int* __restrict__ col,
                                                 float* __restrict__ wn) {
  int i = blockIdx.x * 256 + threadIdx.x;
  int s, d;
  if (i < EE)       { s = ei_s[i];      d = ei_s[EE + i]; }
  else if (i < EE2) { s = ei_t[i - EE] + NN; d = ei_t[i] + NN; }
  else return;
  int p = atomicAdd(&fill[d], 1);
  int idx = indptr[d] + p;
  col[idx] = s;
  wn[idx] = dinv[s] * dinv[d];
}

// ---------------- precision-split kernels ----------------

// both towers' x -> contiguous hi/lo bf16 [NN2, DIN]
__global__ __launch_bounds__(256) void split_x2(const float* __restrict__ x_s,
                                                const float* __restrict__ x_t,
                                                ushortT* __restrict__ hi,
                                                ushortT* __restrict__ lo) {
  const int n4half = NN * DIN / 4;
  int i = blockIdx.x * 256 + threadIdx.x;
  if (i >= 2 * n4half) return;
  float4 v = (i < n4half) ? ((const float4*)x_s)[i] : ((const float4*)x_t)[i - n4half];
  ushort4 h, l;
  h.x = f2bf(v.x); l.x = f2bf(v.x - bf2f(h.x));
  h.y = f2bf(v.y); l.y = f2bf(v.y - bf2f(h.y));
  h.z = f2bf(v.z); l.z = f2bf(v.z - bf2f(h.z));
  h.w = f2bf(v.w); l.w = f2bf(v.w - bf2f(h.w));
  ((ushort4*)hi)[i] = h;
  ((ushort4*)lo)[i] = l;
}

// W [K][256] fp32 -> Wt hi/lo [256][K] bf16 (transpose + split), tiny
__global__ __launch_bounds__(256) void split_w_t(const float* __restrict__ W,
                                                 ushortT* __restrict__ Whi,
                                                 ushortT* __restrict__ Wlo, int K) {
  int idx = blockIdx.x * 256 + threadIdx.x;
  if (idx >= K * 256) return;
  int k = idx >> 8, n = idx & 255;
  float v = W[idx];
  ushortT h = f2bf(v);
  Whi[(size_t)n * K + k] = h;
  Wlo[(size_t)n * K + k] = f2bf(v - bf2f(h));
}

// ---------------- MFMA GEMM (8 waves, single buffer): C[M][256] = A[M][K] @ Wt^T ----
// 512 threads = 8 waves; tile 128 rows x 256 cols. K-chunk 32.
// LDS 48KB: Ahi[0,8K) Alo[8K,16K) Bhi[16K,32K) Blo[32K,48K).
// bf16x3: C = Ah*Bh + Al*Bh + Ah*Bl. Output written as bf16 (hi only).

__global__ __launch_bounds__(512) void gemm_mfma(const ushortT* __restrict__ Ahi,
                                                 const ushortT* __restrict__ Alo,
                                                 const ushortT* __restrict__ Bhi,
                                                 const ushortT* __restrict__ Blo,
                                                 ushortT* __restrict__ C, int M, int K) {
  __shared__ __align__(16) unsigned char smem[49152];
  int tid = threadIdx.x;
  int w = tid >> 6, l = tid & 63;
  int row0 = blockIdx.x * 128;

  f32x4 acc[16];
#pragma unroll
  for (int c = 0; c < 16; ++c) acc[c] = (f32x4)(0.f);

  int arow = w * 16 + (l & 15);
  int grow = row0 + arow;
  if (grow >= M) grow = M - 1;
  const size_t abase = (size_t)grow * K + (size_t)(l >> 4) * 8;
  size_t bkoff = (size_t)(l >> 4) * 8;

  for (int k0 = 0; k0 < K; k0 += 32) {
    gld16(Ahi + abase + k0, smem + w * 1024);
    gld16(Alo + abase + k0, smem + 8192 + w * 1024);
#pragma unroll
    for (int r = 0; r < 2; ++r) {
      int col = (r * 8 + w) * 16 + (l & 15);
      size_t boff = (size_t)col * K + k0 + bkoff;
      gld16(Bhi + boff, smem + 16384 + r * 8192 + w * 1024);
      gld16(Blo + boff, smem + 32768 + r * 8192 + w * 1024);
    }
    __syncthreads();  // drains vmcnt(0): tile ready
    bf16x8 ah = *(const bf16x8*)(smem + tid * 16);
    bf16x8 al = *(const bf16x8*)(smem + 8192 + tid * 16);
#pragma unroll
    for (int c = 0; c < 16; ++c) {
      bf16x8 bh = *(const bf16x8*)(smem + 16384 + (c * 64 + l) * 16);
      bf16x8 bl = *(const bf16x8*)(smem + 32768 + (c * 64 + l) * 16);
      acc[c] = __builtin_amdgcn_mfma_f32_16x16x32_bf16(ah, bh, acc[c], 0, 0, 0);
      acc[c] = __builtin_amdgcn_mfma_f32_16x16x32_bf16(al, bh, acc[c], 0, 0, 0);
      acc[c] = __builtin_amdgcn_mfma_f32_16x16x32_bf16(ah, bl, acc[c], 0, 0, 0);
    }
    __syncthreads();  // all ds_reads done before next stage overwrites
  }
  // store bf16: C[w*16 + (l>>4)*4 + r][c*16 + (l&15)]
  int orow = row0 + w * 16 + (l >> 4) * 4;
#pragma unroll
  for (int r = 0; r < 4; ++r) {
    int rr = orow + r;
    if (rr < M) {
#pragma unroll
      for (int c = 0; c < 16; ++c)
        C[(size_t)rr * HH + c * 16 + (l & 15)] = f2bf(acc[c][r]);
    }
  }
}

// ---------------- CSR gather aggregate (bf16 h rows) -> bf16 hi[/lo] output ----
// out = relu(sum_e wn[e]*h[col[e]] + di^2*h_i + b); one wave per node, lane = 4 feats (8B).

__global__ __launch_bounds__(256) void aggregate_bf(const ushortT* __restrict__ h,
                                                    const int* __restrict__ indptr,
                                                    const int* __restrict__ col,
                                                    const float* __restrict__ wn,
                                                    const float* __restrict__ dinv,
                                                    const float* __restrict__ bias,
                                                    ushortT* __restrict__ ohi,
                                                    ushortT* __restrict__ olo,
                                                    int n, int writeLo) {
  int gw = (blockIdx.x * 256 + threadIdx.x) >> 6;
  int lane = threadIdx.x & 63;
  if (gw >= n) return;
  int beg = indptr[gw], end = indptr[gw + 1];
  float di = dinv[gw];
  float4 acc = make_float4(0.f, 0.f, 0.f, 0.f);
  int e = beg;
  for (; e + 8 <= end; e += 8) {
    int s0 = col[e], s1 = col[e + 1], s2 = col[e + 2], s3 = col[e + 3];
    int s4 = col[e + 4], s5 = col[e + 5], s6 = col[e + 6], s7 = col[e + 7];
    float w0 = wn[e], w1 = wn[e + 1], w2 = wn[e + 2], w3 = wn[e + 3];
    float w4 = wn[e + 4], w5 = wn[e + 5], w6 = wn[e + 6], w7 = wn[e + 7];
    ushort4 r0 = *(const ushort4*)(h + (size_t)s0 * HH + lane * 4);
    ushort4 r1 = *(const ushort4*)(h + (size_t)s1 * HH + lane * 4);
    ushort4 r2 = *(const ushort4*)(h + (size_t)s2 * HH + lane * 4);
    ushort4 r3 = *(const ushort4*)(h + (size_t)s3 * HH + lane * 4);
    ushort4 r4 = *(const ushort4*)(h + (size_t)s4 * HH + lane * 4);
    ushort4 r5 = *(const ushort4*)(h + (size_t)s5 * HH + lane * 4);
    ushort4 r6 = *(const ushort4*)(h + (size_t)s6 * HH + lane * 4);
    ushort4 r7 = *(const ushort4*)(h + (size_t)s7 * HH + lane * 4);
    acc.x += w0 * bf2f(r0.x) + w1 * bf2f(r1.x) + w2 * bf2f(r2.x) + w3 * bf2f(r3.x)
           + w4 * bf2f(r4.x) + w5 * bf2f(r5.x) + w6 * bf2f(r6.x) + w7 * bf2f(r7.x);
    acc.y += w0 * bf2f(r0.y) + w1 * bf2f(r1.y) + w2 * bf2f(r2.y) + w3 * bf2f(r3.y)
           + w4 * bf2f(r4.y) + w5 * bf2f(r5.y) + w6 * bf2f(r6.y) + w7 * bf2f(r7.y);
    acc.z += w0 * bf2f(r0.z) + w1 * bf2f(r1.z) + w2 * bf2f(r2.z) + w3 * bf2f(r3.z)
           + w4 * bf2f(r4.z) + w5 * bf2f(r5.z) + w6 * bf2f(r6.z) + w7 * bf2f(r7.z);
    acc.w += w0 * bf2f(r0.w) + w1 * bf2f(r1.w) + w2 * bf2f(r2.w) + w3 * bf2f(r3.w)
           + w4 * bf2f(r4.w) + w5 * bf2f(r5.w) + w6 * bf2f(r6.w) + w7 * bf2f(r7.w);
  }
  for (; e < end; ++e) {
    int s = col[e];
    float ws = wn[e];
    ushort4 rv = *(const ushort4*)(h + (size_t)s * HH + lane * 4);
    acc.x += ws * bf2f(rv.x); acc.y += ws * bf2f(rv.y);
    acc.z += ws * bf2f(rv.z); acc.w += ws * bf2f(rv.w);
  }
  float selfw = di * di;
  ushort4 sv = *(const ushort4*)(h + (size_t)gw * HH + lane * 4);
  acc.x += selfw * bf2f(sv.x); acc.y += selfw * bf2f(sv.y);
  acc.z += selfw * bf2f(sv.z); acc.w += selfw * bf2f(sv.w);
  const float4 bv = *(const float4*)(bias + lane * 4);
  float o0 = fmaxf(acc.x + bv.x, 0.f);
  float o1 = fmaxf(acc.y + bv.y, 0.f);
  float o2 = fmaxf(acc.z + bv.z, 0.f);
  float o3 = fmaxf(acc.w + bv.w, 0.f);
  ushort4 hvec;
  hvec.x = f2bf(o0); hvec.y = f2bf(o1); hvec.z = f2bf(o2); hvec.w = f2bf(o3);
  *(ushort4*)(ohi + (size_t)gw * HH + lane * 4) = hvec;
  if (writeLo) {
    ushort4 lvec;
    lvec.x = f2bf(o0 - bf2f(hvec.x));
    lvec.y = f2bf(o1 - bf2f(hvec.y));
    lvec.z = f2bf(o2 - bf2f(hvec.z));
    lvec.w = f2bf(o3 - bf2f(hvec.w));
    *(ushort4*)(olo + (size_t)gw * HH + lane * 4) = lvec;
  }
}

// ---------------- fused pair MLP (MFMA, 8 waves; A hi-only, B hi/lo) ----------------
// A row p = concat(xl[y0[p]], xr[y1[p]]) [512]; hidden = relu(A@fcW + fcb); out = sigmoid(hidden.w2 + b2)
// 512 threads; tile 128 pairs x 256 cols; LDS 40KB: A[0,8K) Bhi[8K,24K) Blo[24K,40K).

__global__ __launch_bounds__(512) void mlp_mfma(const ushortT* __restrict__ XLhi,
                                                const ushortT* __restrict__ XRhi,
                                                const int* __restrict__ y,
                                                const ushortT* __restrict__ Bhi,
                                                const ushortT* __restrict__ Blo,
                                                const float* __restrict__ fcb,
                                                const float* __restrict__ w2,
                                                const float* __restrict__ b2,
                                                float* __restrict__ out, int P) {
  __shared__ __align__(16) unsigned char smem[40960];
  __shared__ int ynode[2][128];
  int tid = threadIdx.x;
  int w = tid >> 6, l = tid & 63;
  int p0 = blockIdx.x * 128;
  if (tid < 256) {
    int side = tid >> 7, r = tid & 127;
    int p = p0 + r;
    if (p >= P) p = P - 1;
    ynode[side][r] = y[2 * p + side];
  }
  __syncthreads();

  f32x4 acc[16];
#pragma unroll
  for (int c = 0; c < 16; ++c) acc[c] = (f32x4)(0.f);

  int arow = w * 16 + (l & 15);
  int akg = l >> 4;
  int nL = ynode[0][arow];
  int nR = ynode[1][arow];

  for (int kt = 0; kt < 16; ++kt) {
    int k0 = kt * 32;
    {
      const ushortT* shi = (kt < 8) ? XLhi : XRhi;
      int node = (kt < 8) ? nL : nR;
      int kk = (kt < 8) ? k0 : k0 - 256;
      size_t aoff = (size_t)node * HH + kk + akg * 8;
      gld16(shi + aoff, smem + w * 1024);
      size_t bkoff = (size_t)akg * 8;
#pragma unroll
      for (int r = 0; r < 2; ++r) {
        int colc = (r * 8 + w) * 16 + (l & 15);
        size_t boff = (size_t)colc * 512 + k0 + bkoff;
        gld16(Bhi + boff, smem + 8192 + r * 8192 + w * 1024);
        gld16(Blo + boff, smem + 24576 + r * 8192 + w * 1024);
      }
    }
    __syncthreads();
    bf16x8 ah = *(const bf16x8*)(smem + tid * 16);
#pragma unroll
    for (int c = 0; c < 16; ++c) {
      bf16x8 bh = *(const bf16x8*)(smem + 8192 + (c * 64 + l) * 16);
      bf16x8 bl = *(const bf16x8*)(smem + 24576 + (c * 64 + l) * 16);
      acc[c] = __builtin_amdgcn_mfma_f32_16x16x32_bf16(ah, bh, acc[c], 0, 0, 0);
      acc[c] = __builtin_amdgcn_mfma_f32_16x16x32_bf16(ah, bl, acc[c], 0, 0, 0);
    }
    __syncthreads();
  }
  // epilogue: bias+relu, dot w2 across cols; reduce over 16 lanes of each row group
  float part[4] = {0.f, 0.f, 0.f, 0.f};
  int cb = l & 15;
#pragma unroll
  for (int c = 0; c < 16; ++c) {
    int colc = c * 16 + cb;
    float bv = fcb[colc];
    float wv = w2[colc];
#pragma unroll
    for (int r = 0; r < 4; ++r) part[r] += fmaxf(acc[c][r] + bv, 0.f) * wv;
  }
  float bias2 = b2[0];
#pragma unroll
  for (int r = 0; r < 4; ++r) {
    float s = part[r];
    s += __shfl_xor(s, 1);
    s += __shfl_xor(s, 2);
    s += __shfl_xor(s, 4);
    s += __shfl_xor(s, 8);
    if ((l & 15) == 0) {
      int p = p0 + w * 16 + (l >> 4) * 4 + r;
      if (p < P) out[p] = 1.f / (1.f + expf(-(s + bias2)));
    }
  }
}

// ---------------- launch ----------------

extern "C" void kernel_launch(void* const* d_in, const int* in_sizes, int n_in,
                              void* d_out, int out_size, void* d_ws, size_t ws_size,
                              hipStream_t stream) {
  const float* x_s  = (const float*)d_in[0];
  const float* x_t  = (const float*)d_in[1];
  const int*   ei_s = (const int*)d_in[2];
  const int*   ei_t = (const int*)d_in[3];
  const int*   y    = (const int*)d_in[4];
  const float* W1   = (const float*)d_in[5];
  const float* b1   = (const float*)d_in[6];
  const float* W2   = (const float*)d_in[7];
  const float* b2   = (const float*)d_in[8];
  const float* fcW  = (const float*)d_in[9];
  const float* fcb  = (const float*)d_in[10];
  const float* fc2W = (const float*)d_in[11];
  const float* fc2b = (const float*)d_in[12];
  float* out = (float*)d_out;

  char* ws = (char*)d_ws;
  size_t off = 0;
  auto alloc = [&](size_t bytes) -> void* {
    void* p = ws + off;
    off += (bytes + 255) & ~(size_t)255;
    return p;
  };
  ushortT* hb_bf   = (ushortT*)alloc((size_t)NN2 * HH * 2);   // GEMM output (bf16 hi)
  ushortT* tmp_hi  = (ushortT*)alloc((size_t)NN2 * HH * 2);
  ushortT* tmp_lo  = (ushortT*)alloc((size_t)NN2 * HH * 2);
  ushortT* xlr_hi  = (ushortT*)alloc((size_t)NN2 * HH * 2);   // [xl ; xr]
  ushortT* xa_hi   = (ushortT*)alloc((size_t)NN2 * DIN * 2);
  ushortT* xa_lo   = (ushortT*)alloc((size_t)NN2 * DIN * 2);
  ushortT* W1t_hi  = (ushortT*)alloc((size_t)HH * DIN * 2);
  ushortT* W1t_lo  = (ushortT*)alloc((size_t)HH * DIN * 2);
  ushortT* W2t_hi  = (ushortT*)alloc((size_t)HH * HH * 2);
  ushortT* W2t_lo  = (ushortT*)alloc((size_t)HH * HH * 2);
  ushortT* fct_hi  = (ushortT*)alloc((size_t)HH * 512 * 2);
  ushortT* fct_lo  = (ushortT*)alloc((size_t)HH * 512 * 2);
  int* cnt      = (int*)alloc((size_t)NN2 * 4);
  float* dinv   = (float*)alloc((size_t)NN2 * 4);
  int* indptr   = (int*)alloc((size_t)(NN2 + 1) * 4);
  int* fill     = (int*)alloc((size_t)NN2 * 4);
  int* col      = (int*)alloc((size_t)EE2 * 4);
  float* wn     = (float*)alloc((size_t)EE2 * 4);
  int* bsum     = (int*)alloc(2048 * 4);

  hipMemsetAsync(cnt, 0, (size_t)NN2 * 4, stream);
  hipMemsetAsync(fill, 0, (size_t)NN2 * 4, stream);

  const int NB2 = (NN2 + 255) / 256;         // 391
  const int EB2 = (EE2 + 255) / 256;         // 3907
  const int XB2 = (NN2 * DIN / 4 + 255) / 256;
  const int GB  = (NN2 + 127) / 128;         // 782
  const int AB  = (NN2 * 64 + 255) / 256;    // 25000

  // weight splits (tiny)
  split_w_t<<<(DIN * HH + 255) / 256, 256, 0, stream>>>(W1, W1t_hi, W1t_lo, DIN);
  split_w_t<<<(HH * HH + 255) / 256, 256, 0, stream>>>(W2, W2t_hi, W2t_lo, HH);
  split_w_t<<<(512 * HH + 255) / 256, 256, 0, stream>>>(fcW, fct_hi, fct_lo, 512);

  // batched CSR (both graphs)
  count_deg2<<<EB2, 256, 0, stream>>>(ei_s + EE, ei_t + EE, cnt);
  compute_dinv<<<NB2, 256, 0, stream>>>(cnt, dinv, NN2);
  scan_block<<<NB2, 256, 0, stream>>>(cnt, indptr, bsum, NN2);
  scan_totals<<<1, 512, 0, stream>>>(bsum, NB2);
  scan_add<<<NB2, 256, 0, stream>>>(indptr, bsum, cnt, NN2);
  fill_csr2<<<EB2, 256, 0, stream>>>(ei_s, ei_t, indptr, dinv, fill, col, wn);

  // batched towers
  split_x2<<<XB2, 256, 0, stream>>>(x_s, x_t, xa_hi, xa_lo);
  gemm_mfma<<<GB, 512, 0, stream>>>(xa_hi, xa_lo, W1t_hi, W1t_lo, hb_bf, NN2, DIN);
  aggregate_bf<<<AB, 256, 0, stream>>>(hb_bf, indptr, col, wn, dinv, b1, tmp_hi, tmp_lo, NN2, 1);
  gemm_mfma<<<GB, 512, 0, stream>>>(tmp_hi, tmp_lo, W2t_hi, W2t_lo, hb_bf, NN2, HH);
  aggregate_bf<<<AB, 256, 0, stream>>>(hb_bf, indptr, col, wn, dinv, b2, xlr_hi, xlr_hi, NN2, 0);
  // fused pair MLP (xl = rows 0..NN, xr = rows NN..2NN)
  mlp_mfma<<<(PP + 127) / 128, 512, 0, stream>>>(xlr_hi, xlr_hi + (size_t)NN * HH, y,
                                                 fct_hi, fct_lo, fcb, fc2W, fc2b, out, PP);
}